// Round 5
// baseline (709.584 us; speedup 1.0000x reference)
//
#include <hip/hip_runtime.h>
#include <cmath>
#include <utility>
#include <cstddef>

// ===========================================================================
// Quantum circuit simulation: 16 qubits, 4 StronglyEntanglingLayers.
// CNOTs are GF(2)-linear index permutations -> tracked symbolically in a
// bit-matrix M (zero data movement). Only 64 Rot gates touch amplitudes:
// pairs (p, p^mask), mask = column of M, branch bit = parity(row of M^{-1}
// & p). A constexpr greedy groups gates into passes whose masks fit in a
// 14-dim GF(2) subspace: 6 seeded lane dims (bits 0-5, coalescing) +
// 5 reg dims + 3 WAVE dims -> 5 passes. Cross-wave gates exchange via a
// 64 KiB LDS side-stage (only the side-1 half of each pair is staged;
// side-0 threads compute BOTH pair outputs and write the partner's result
// back). 64 KiB LDS -> 2 WGs/CU (16 waves) vs 1 WG at 128 KiB: doubles
// latency hiding for the load/store phases that dominated at 20% occupancy.
// ===========================================================================

namespace qsim {

constexpr int NQ = 16;
constexpr int NL = 4;
constexpr int NGMAX = 12;   // max groups (passes); greedy yields 5
constexpr int GMAX  = 36;   // max gates per group (max seen: 15)
constexpr int BDIM  = 14;   // 6 lane (seeded) + 5 reg + 3 wave dims
constexpr int CDIM  = 2;    // complement dims (coset bits)

constexpr int parity16(unsigned v) {
    int p = 0;
    for (int k = 0; k < 16; ++k) p ^= (int)((v >> k) & 1u);
    return p;
}

struct PlanT {
    int ngroups;
    int ng[NGMAX];
    unsigned char gl[NGMAX][GMAX];     // layer
    unsigned char gw[NGMAX][GMAX];     // wire
    unsigned short mloc[NGMAX][GMAX];  // 14-bit local mask (0-5 lane, 6-10 reg, 11-13 wave)
    unsigned short rloc[NGMAX][GMAX];  // 14-bit local row-parity vector
    unsigned short grow[NGMAX][GMAX];  // 16-bit global row (for base parity)
    unsigned short V[NGMAX][BDIM];     // basis; V[0..5] == {1,2,4,8,16,32}
    unsigned short U[NGMAX][CDIM];     // complement unit vectors (coset bits)
    unsigned short frow[16];           // rows of final M^{-1}
    unsigned short floc[16];           // frow parities over last group's basis
    bool ok;
};

constexpr PlanT make_plan() {
    PlanT P{};
    P.ok = true;

    // ---- per-gate mask (column of M) and row (row of M^{-1}) ----
    unsigned col[16] = {}, rowv[16] = {};
    for (int b = 0; b < 16; ++b) { col[b] = 1u << b; rowv[b] = 1u << b; }
    unsigned gmask[64] = {}, growg[64] = {};
    unsigned char glay[64] = {}, gwire[64] = {};
    int gi = 0;
    for (int l = 0; l < NL; ++l) {
        for (int w = 0; w < NQ; ++w) {
            const int b = 15 - w;
            gmask[gi] = col[b]; growg[gi] = rowv[b];
            glay[gi] = (unsigned char)l; gwire[gi] = (unsigned char)w; ++gi;
        }
        const int r = (l % (NQ - 1)) + 1;
        for (int w = 0; w < NQ; ++w) {
            const int cb = 15 - w;
            const int tb = 15 - ((w + r) % NQ);
            col[cb] ^= col[tb];      // M' = M * C  (column update)
            rowv[tb] ^= rowv[cb];    // M'^{-1} = C * M^{-1} (row update)
        }
    }
    for (int b = 0; b < 16; ++b) P.frow[b] = (unsigned short)rowv[b];

    // sanity: row_b(M^{-1}) . col_b'(M) == delta
    for (int a = 0; a < 16; ++a)
        for (int b2 = 0; b2 < 16; ++b2)
            if (parity16(rowv[a] & col[b2]) != (a == b2 ? 1 : 0)) P.ok = false;
    // sanity: per gate, row . mask == 1
    for (int i = 0; i < 64; ++i)
        if (parity16(gmask[i] & growg[i]) != 1) P.ok = false;

    // ---- greedy grouping: layer-monotone groups; basis seeded with the 6
    //      low unit bits (lane dims) so global access is always coalesced ----
    bool applied[64] = {};
    int napplied = 0;
    int grp = 0;
    while (napplied < 64) {
        if (grp >= NGMAX) { P.ok = false; break; }
        unsigned B[BDIM] = {}; int piv[BDIM] = {}; int nb = 0;
        // seed: lane dims = bits 0..5 (coalescing guarantee). Seeds are never
        // modified by back-reduction (non-seed pivots are bits >= 6).
        for (int i = 0; i < 6; ++i) { B[i] = 1u << i; piv[i] = i; ++nb; }
        unsigned tmask[GMAX] = {}, trow[GMAX] = {};
        int cnt = 0;
        bool progress = true;
        while (progress) {
            progress = false;
            int lay = -1;
            for (int i = 0; i < 64; ++i)
                if (!applied[i]) { lay = glay[i]; break; }
            if (lay < 0) break;
            for (int w = 15; w >= 0; --w) {   // descending wire scan
                const int idx = lay * 16 + w;
                if (applied[idx]) continue;
                unsigned v = gmask[idx];
                for (int i = 0; i < nb; ++i) if ((v >> piv[i]) & 1u) v ^= B[i];
                if (v != 0u && nb == BDIM) continue;   // doesn't fit
                if (cnt >= GMAX) { P.ok = false; continue; }
                if (v != 0u) {
                    int pb = 0; while (((v >> pb) & 1u) == 0u) ++pb;
                    for (int i = 0; i < nb; ++i) if ((B[i] >> pb) & 1u) B[i] ^= v;
                    B[nb] = v; piv[nb] = pb; ++nb;     // RREF maintained
                }
                P.gl[grp][cnt] = glay[idx];
                P.gw[grp][cnt] = gwire[idx];
                tmask[cnt] = gmask[idx]; trow[cnt] = growg[idx];
                ++cnt;
                applied[idx] = true; ++napplied; progress = true;
            }
        }
        // pad basis to 14 with (reduced) unit vectors, low bits first
        for (int bbit = 0; bbit < 16 && nb < BDIM; ++bbit) {
            unsigned v = 1u << bbit;
            for (int i = 0; i < nb; ++i) if ((v >> piv[i]) & 1u) v ^= B[i];
            if (v != 0u) {
                int pb = 0; while (((v >> pb) & 1u) == 0u) ++pb;
                for (int i = 0; i < nb; ++i) if ((B[i] >> pb) & 1u) B[i] ^= v;
                B[nb] = v; piv[nb] = pb; ++nb;
            }
        }
        if (nb != BDIM) P.ok = false;
        for (int i = 0; i < 6; ++i) if (B[i] != (1u << i)) P.ok = false;

        // provisional coords over basis order (seeds 0-5, insertion 6-13)
        unsigned provml[GMAX] = {};
        for (int g = 0; g < cnt; ++g) {
            unsigned m = tmask[g], ml = 0;
            for (int i = 0; i < BDIM; ++i)
                if ((m >> piv[i]) & 1u) { ml |= 1u << i; m ^= B[i]; }
            if (m != 0u) P.ok = false;
            if (ml == 0u) P.ok = false;
            provml[g] = ml;
        }
        // usage count per non-seed dim; most-used 5 -> reg slots (6-10),
        // least-used 3 -> wave slots (11-13, LDS-exchange gates)
        int usage[BDIM] = {};
        for (int g = 0; g < cnt; ++g)
            for (int i = 6; i < BDIM; ++i)
                if ((provml[g] >> i) & 1u) usage[i]++;
        int ord[8] = {};
        for (int k = 0; k < 8; ++k) ord[k] = 6 + k;
        for (int i = 1; i < 8; ++i) {       // stable insertion sort, desc usage
            int oi = ord[i]; int j = i - 1;
            while (j >= 0 && usage[ord[j]] < usage[oi]) { ord[j+1] = ord[j]; --j; }
            ord[j+1] = oi;
        }
        int slot[BDIM] = {};
        for (int i = 0; i < 6; ++i) slot[i] = i;
        for (int k = 0; k < 8; ++k) slot[ord[k]] = 6 + k;
        // final basis + remapped coords + row parities
        for (int i = 0; i < 6; ++i) P.V[grp][i] = (unsigned short)B[i];
        for (int k = 0; k < 8; ++k) P.V[grp][6 + k] = (unsigned short)B[ord[k]];
        for (int g = 0; g < cnt; ++g) {
            unsigned ml = 0;
            for (int i = 0; i < BDIM; ++i)
                if ((provml[g] >> i) & 1u) ml |= 1u << slot[i];
            P.mloc[grp][g] = (unsigned short)ml;
            unsigned rl = 0;
            for (int s = 0; s < BDIM; ++s)
                rl |= (unsigned)parity16(trow[g] & P.V[grp][s]) << s;
            P.rloc[grp][g] = (unsigned short)rl;
            P.grow[grp][g] = (unsigned short)trow[g];
        }
        // complement unit vectors = non-pivot bits
        int cu = 0;
        for (int bbit = 0; bbit < 16; ++bbit) {
            bool isp = false;
            for (int i = 0; i < BDIM; ++i) if (piv[i] == bbit) isp = true;
            if (!isp) { if (cu < CDIM) P.U[grp][cu] = (unsigned short)(1u << bbit); ++cu; }
        }
        if (cu != CDIM) P.ok = false;
        P.ng[grp] = cnt;
        ++grp;
    }
    P.ngroups = grp;
    // measurement row parities in LAST group's (final-ordered) basis
    for (int q = 0; q < 16; ++q) {
        unsigned rl = 0;
        for (int s = 0; s < BDIM; ++s)
            rl |= (unsigned)parity16(P.frow[q] & P.V[P.ngroups - 1][s]) << s;
        P.floc[q] = (unsigned short)rl;
    }
    return P;
}

constexpr PlanT PLAN = make_plan();
static_assert(PLAN.ok, "constexpr plan construction failed");
static_assert(PLAN.ngroups >= 2 && PLAN.ngroups <= NGMAX, "unexpected group count");

// ---------------------------------------------------------------------------
// device code
// ---------------------------------------------------------------------------

template<int G>
__device__ __forceinline__ unsigned regxor(int r) {
    unsigned rx = 0;
    if (r & 1)  rx ^= PLAN.V[G][6];
    if (r & 2)  rx ^= PLAN.V[G][7];
    if (r & 4)  rx ^= PLAN.V[G][8];
    if (r & 8)  rx ^= PLAN.V[G][9];
    if (r & 16) rx ^= PLAN.V[G][10];
    return rx;
}

template<int G>
__device__ __forceinline__ unsigned wavexor(int wv) {
    unsigned rx = 0;
    if (wv & 1) rx ^= PLAN.V[G][11];
    if (wv & 2) rx ^= PLAN.V[G][12];
    if (wv & 4) rx ^= PLAN.V[G][13];
    return rx;
}

// drop bit sbpos from a 14-bit local index -> 13-bit LDS slot.
// All staged indices have bit sbpos == 1, so the drop is bijective.
__device__ __forceinline__ unsigned compress14(unsigned idx, int sbpos) {
    return (idx & ((1u << sbpos) - 1u)) | ((idx >> (sbpos + 1)) << sbpos);
}

// tfix = (wave<<11) | lane : the thread-fixed local-index bits
template<int G, int g>
__device__ __forceinline__ void apply_gates(float (&re)[32], float (&im)[32],
                                            const float* __restrict__ gu,
                                            unsigned base, int tfix,
                                            float2* tile)
{
    if constexpr (g < PLAN.ng[G]) {
        constexpr int lq = PLAN.gl[G][g];
        constexpr int wq = PLAN.gw[G][g];
        constexpr unsigned ml = PLAN.mloc[G][g];
        constexpr unsigned rl = PLAN.rloc[G][g];
        constexpr unsigned grw = PLAN.grow[G][g];
        constexpr unsigned mlane = ml & 63u;
        constexpr unsigned mreg = (ml >> 6) & 31u;
        constexpr unsigned mwav = ml >> 11;

        const float* up = gu + (lq * 16 + wq) * 8;  // uniform (scalar) loads
        const float U00r = up[0], U00i = up[1];
        const float U01r = up[2], U01i = up[3];
        const float U10r = up[4], U10i = up[5];
        const float U11r = up[6], U11i = up[7];

        // thread-fixed parity from coset base + lane/wave bits
        const int pt = (__popc(grw & base) ^ __popc(rl & (unsigned)tfix)) & 1;
        // coefficients for amps with total parity 0 (E0,F0) and parity 1 (E1,F1)
        const float E0r = pt ? U11r : U00r, E0i = pt ? U11i : U00i;
        const float F0r = pt ? U10r : U01r, F0i = pt ? U10i : U01i;
        const float E1r = pt ? U00r : U11r, E1i = pt ? U00i : U11i;
        const float F1r = pt ? U01r : U10r, F1i = pt ? U01i : U10i;

        if constexpr (mwav != 0u) {
            // cross-wave side-stage through 64 KiB LDS (2^13 slots).
            // sb = lowest wave bit of the mask; side1 threads (bit set) stage
            // their values; side0 threads compute BOTH pair outputs (partner
            // parity = own parity ^ 1, since row.mask == 1) and write the
            // partner's new value back; side1 reads it. Branches are
            // wave-uniform; LDS addresses stay 512B-contiguous per wave.
            constexpr int sbpos = (mwav & 1u) ? 11 : ((mwav & 2u) ? 12 : 13);
            constexpr unsigned sbit = 1u << sbpos;
            const bool side1 = ((unsigned)tfix & sbit) != 0u;
            if (side1) {
                #pragma unroll
                for (int r = 0; r < 32; ++r)
                    tile[compress14((unsigned)(tfix | (r << 6)), sbpos)] =
                        make_float2(re[r], im[r]);
            }
            __syncthreads();
            if (!side1) {
                #pragma unroll
                for (int r = 0; r < 32; ++r) {
                    const unsigned own = (unsigned)(tfix | (r << 6));
                    const unsigned a13 = compress14(own ^ ml, sbpos);
                    const float2 p = tile[a13];
                    const bool cp = (__popc(rl & ((unsigned)r << 6)) & 1) != 0;
                    const float Er = cp ? E1r : E0r, Ei = cp ? E1i : E0i;
                    const float Fr = cp ? F1r : F0r, Fi = cp ? F1i : F0i;
                    const float Gr = cp ? E0r : E1r, Gi = cp ? E0i : E1i;
                    const float Hr = cp ? F0r : F1r, Hi = cp ? F0i : F1i;
                    const float ar = re[r], ai = im[r];
                    re[r] = Er*ar - Ei*ai + Fr*p.x - Fi*p.y;
                    im[r] = Er*ai + Ei*ar + Fr*p.y + Fi*p.x;
                    tile[a13] = make_float2(Gr*p.x - Gi*p.y + Hr*ar - Hi*ai,
                                            Gr*p.y + Gi*p.x + Hr*ai + Hi*ar);
                }
            }
            __syncthreads();
            if (side1) {
                #pragma unroll
                for (int r = 0; r < 32; ++r) {
                    const float2 v =
                        tile[compress14((unsigned)(tfix | (r << 6)), sbpos)];
                    re[r] = v.x; im[r] = v.y;
                }
            }
            __syncthreads();   // WAR: protect slots before next gate stages
        } else if constexpr (mlane == 0u) {
            // pure register pairs (r, r^mreg) within the thread
            constexpr unsigned lb = mreg & (0u - mreg);
            #pragma unroll
            for (int r = 0; r < 32; ++r) {
                if (((unsigned)r & lb) == 0u) {
                    const int k = r ^ (int)mreg;
                    const bool cp = (__popc(rl & ((unsigned)r << 6)) & 1) != 0;
                    const float Ear = cp ? E1r : E0r, Eai = cp ? E1i : E0i;
                    const float Far = cp ? F1r : F0r, Fai = cp ? F1i : F0i;
                    const float Ebr = cp ? E0r : E1r, Ebi = cp ? E0i : E1i;
                    const float Fbr = cp ? F0r : F1r, Fbi = cp ? F0i : F1i;
                    const float ar = re[r], ai = im[r], br = re[k], bi = im[k];
                    re[r] = Ear*ar - Eai*ai + Far*br - Fai*bi;
                    im[r] = Ear*ai + Eai*ar + Far*bi + Fai*br;
                    re[k] = Ebr*br - Ebi*bi + Fbr*ar - Fbi*ai;
                    im[k] = Ebr*bi + Ebi*br + Fbr*ai + Fbi*ar;
                }
            }
        } else if constexpr (mreg == 0u) {
            // cross-lane only: partner = same reg on lane^mlane
            #pragma unroll
            for (int r = 0; r < 32; ++r) {
                const float pr = __shfl_xor(re[r], (int)mlane, 64);
                const float pi = __shfl_xor(im[r], (int)mlane, 64);
                const bool cp = (__popc(rl & ((unsigned)r << 6)) & 1) != 0;
                const float Er = cp ? E1r : E0r, Ei = cp ? E1i : E0i;
                const float Fr = cp ? F1r : F0r, Fi = cp ? F1i : F0i;
                const float ar = re[r], ai = im[r];
                re[r] = Er*ar - Ei*ai + Fr*pr - Fi*pi;
                im[r] = Er*ai + Ei*ar + Fr*pi + Fi*pr;
            }
        } else {
            // mixed lane+reg: partner = reg r^mreg on lane^mlane; prefetch
            // both directions of each reg pair via shfl BEFORE writing either.
            constexpr unsigned lb = mreg & (0u - mreg);
            #pragma unroll
            for (int r = 0; r < 32; ++r) {
                if (((unsigned)r & lb) == 0u) {
                    const int k = r ^ (int)mreg;
                    const float prr = __shfl_xor(re[k], (int)mlane, 64);
                    const float pri = __shfl_xor(im[k], (int)mlane, 64);
                    const float pkr = __shfl_xor(re[r], (int)mlane, 64);
                    const float pki = __shfl_xor(im[r], (int)mlane, 64);
                    const bool cpr = (__popc(rl & ((unsigned)r << 6)) & 1) != 0;
                    const bool cpk = (__popc(rl & ((unsigned)k << 6)) & 1) != 0;
                    {
                        const float Er = cpr ? E1r : E0r, Ei = cpr ? E1i : E0i;
                        const float Fr = cpr ? F1r : F0r, Fi = cpr ? F1i : F0i;
                        const float ar = re[r], ai = im[r];
                        re[r] = Er*ar - Ei*ai + Fr*prr - Fi*pri;
                        im[r] = Er*ai + Ei*ar + Fr*pri + Fi*prr;
                    }
                    {
                        const float Er = cpk ? E1r : E0r, Ei = cpk ? E1i : E0i;
                        const float Fr = cpk ? F1r : F0r, Fi = cpk ? F1i : F0i;
                        const float ar = re[k], ai = im[k];
                        re[k] = Er*ar - Ei*ai + Fr*pkr - Fi*pki;
                        im[k] = Er*ai + Ei*ar + Fr*pki + Fi*pkr;
                    }
                }
            }
        }
        apply_gates<G, g + 1>(re, im, gu, base, tfix, tile);
    }
}

// one 512-thread WG = one (batch, coset) tile of 2^14 amplitudes,
// 32 complex/thread; 8 waves; cross-wave gates via 64 KiB LDS side-stage.
// launch_bounds(512,4): 4 waves/EU = 2 WGs/CU (VGPR<=128, LDS 2x64KiB).
template<int G, bool FIRST, bool LAST>
__global__ __launch_bounds__(512, 4)
void pass_kernel(const float* __restrict__ x,
                 const float* __restrict__ gu,
                 float2* __restrict__ state,
                 const float* __restrict__ invn,
                 float* __restrict__ zpart)
{
    __shared__ float2 tile[1 << 13];   // 64 KiB side-stage
    const int lane = (int)(threadIdx.x & 63u);
    const int wave = (int)(threadIdx.x >> 6);
    const int batch = (int)blockIdx.x >> 2;
    const unsigned coset = (unsigned)blockIdx.x & 3u;

    unsigned base = 0;
    if (coset & 1u) base ^= PLAN.U[G][0];
    if (coset & 2u) base ^= PLAN.U[G][1];
    // lane dims are literal bits 0-5 -> contiguous 64 x float2 per wave
    const unsigned pfix = base ^ (unsigned)lane ^ wavexor<G>(wave);
    const int tfix = (wave << 11) | lane;
    const int boff = batch << 16;

    float re[32], im[32];
    if constexpr (FIRST) {
        const float inv = invn[batch];
        #pragma unroll
        for (int r = 0; r < 32; ++r) {
            re[r] = x[boff + (int)(pfix ^ regxor<G>(r))] * inv;
            im[r] = 0.f;
        }
    } else {
        #pragma unroll
        for (int r = 0; r < 32; ++r) {
            const float2 v = state[boff + (int)(pfix ^ regxor<G>(r))];
            re[r] = v.x; im[r] = v.y;
        }
    }

    apply_gates<G, 0>(re, im, gu, base, tfix, tile);

    if constexpr (LAST) {
        // <Z_q> partials: sign = parity(frow[q] & p)
        float acc[16];
        #pragma unroll
        for (int q = 0; q < 16; ++q) acc[q] = 0.f;
        #pragma unroll
        for (int r = 0; r < 32; ++r) {
            const float p = re[r]*re[r] + im[r]*im[r];
            #pragma unroll
            for (int q = 0; q < 16; ++q) {
                const bool sp = (__popc((unsigned)PLAN.floc[q] & ((unsigned)r << 6)) & 1) != 0;
                acc[q] += sp ? -p : p;
            }
        }
        const int W = (int)blockIdx.x * 8 + wave;
        #pragma unroll
        for (int q = 0; q < 16; ++q) {
            const int fl = (__popc((unsigned)PLAN.frow[q] & base) ^
                            __popc((unsigned)PLAN.floc[q] & (unsigned)tfix)) & 1;
            float v = fl ? -acc[q] : acc[q];
            #pragma unroll
            for (int o = 32; o; o >>= 1) v += __shfl_xor(v, o, 64);
            if (lane == 0) zpart[W * 16 + q] = v;
        }
    } else {
        #pragma unroll
        for (int r = 0; r < 32; ++r)
            state[boff + (int)(pfix ^ regxor<G>(r))] = make_float2(re[r], im[r]);
    }
}

__global__ __launch_bounds__(256)
void norm_kernel(const float* __restrict__ x, float* __restrict__ invn)
{
    const int b = (int)blockIdx.x;
    const float4* xv = reinterpret_cast<const float4*>(x + ((size_t)b << 16));
    float s = 0.f;
    for (int i = (int)threadIdx.x; i < 16384; i += 256) {
        const float4 v = xv[i];
        s += v.x*v.x + v.y*v.y + v.z*v.z + v.w*v.w;
    }
    #pragma unroll
    for (int o = 32; o; o >>= 1) s += __shfl_xor(s, o, 64);
    __shared__ float partial[4];
    if ((threadIdx.x & 63u) == 0u) partial[threadIdx.x >> 6] = s;
    __syncthreads();
    if (threadIdx.x == 0) {
        const float t = partial[0] + partial[1] + partial[2] + partial[3];
        invn[b] = 1.0f / sqrtf(t);
    }
}

// precompute the 64 Rot matrices (PennyLane Rot = RZ(om) RY(th) RZ(phi))
__global__ void gateu_kernel(const float* __restrict__ wts, float* __restrict__ gu)
{
    const int i = (int)threadIdx.x;  // gate index l*16+w
    if (i < 64) {
        const float phi = wts[i*3+0], th = wts[i*3+1], om = wts[i*3+2];
        float sh, ch; sincosf(0.5f * th, &sh, &ch);
        float sap, cap; sincosf(0.5f * (phi + om), &sap, &cap);
        float sam, cam; sincosf(0.5f * (phi - om), &sam, &cam);
        gu[i*8+0] =  cap*ch;  gu[i*8+1] = -sap*ch;   // U00 = e^{-i(phi+om)/2} c
        gu[i*8+2] = -cam*sh;  gu[i*8+3] = -sam*sh;   // U01 = -e^{ i(phi-om)/2} s
        gu[i*8+4] =  cam*sh;  gu[i*8+5] = -sam*sh;   // U10 =  e^{-i(phi-om)/2} s
        gu[i*8+6] =  cap*ch;  gu[i*8+7] =  sap*ch;   // U11 =  e^{ i(phi+om)/2} c
    }
}

__global__ __launch_bounds__(512)
void out_kernel(const float* __restrict__ zpart, const float* __restrict__ cw,
                const float* __restrict__ cb, float* __restrict__ out)
{
    const int b = (int)blockIdx.x;
    const int q = (int)(threadIdx.x >> 5);
    const int c = (int)(threadIdx.x & 31u);
    float v = zpart[(size_t)(((b << 5) | c) * 16 + q)];
    #pragma unroll
    for (int o = 16; o; o >>= 1) v += __shfl_xor(v, o, 32);
    __shared__ float z[16];
    if (c == 0) z[q] = v;
    __syncthreads();
    if (threadIdx.x < 2) {
        const int o = (int)threadIdx.x;
        float acc = cb[o];
        #pragma unroll
        for (int w = 0; w < 16; ++w) acc += cw[o * 16 + w] * z[15 - w];
        out[b * 2 + o] = acc;
    }
}

__global__ void sentinel_kernel(float* out)
{
    if (threadIdx.x < 256) out[threadIdx.x] = -12345.0f;  // ws too small marker
}

template<int I>
static void launch_one(const float* x, const float* gu, float2* state,
                       const float* invn, float* zpart, hipStream_t s)
{
    pass_kernel<I, I == 0, I == PLAN.ngroups - 1>
        <<<512, 512, 0, s>>>(x, gu, state, invn, zpart);
}

template<std::size_t... I>
static void launch_all(std::index_sequence<I...>, const float* x, const float* gu,
                       float2* state, const float* invn, float* zpart, hipStream_t s)
{
    (launch_one<(int)I>(x, gu, state, invn, zpart, s), ...);
}

} // namespace qsim

extern "C" void kernel_launch(void* const* d_in, const int* in_sizes, int n_in,
                              void* d_out, int out_size, void* d_ws, size_t ws_size,
                              hipStream_t stream)
{
    (void)in_sizes; (void)n_in; (void)out_size;
    const float* x   = (const float*)d_in[0];   // (128,256,256) f32
    const float* wts = (const float*)d_in[1];   // (4,16,3) f32
    const float* cw  = (const float*)d_in[2];   // (2,16) f32
    const float* cb  = (const float*)d_in[3];   // (2,) f32
    float* out = (float*)d_out;                 // (128,2) f32

    constexpr size_t STATE_BYTES = (size_t)128 * 65536 * sizeof(float2); // 64 MiB
    constexpr size_t INVN_OFF  = STATE_BYTES;                  // 128 floats
    constexpr size_t GATEU_OFF = STATE_BYTES + 1024;           // 64*8 floats
    constexpr size_t ZPART_OFF = STATE_BYTES + 1024 + 4096;    // 4096*16 floats
    constexpr size_t NEED = ZPART_OFF + (size_t)4096 * 16 * sizeof(float);

    if (ws_size < NEED) {
        qsim::sentinel_kernel<<<1, 256, 0, stream>>>(out);
        return;
    }

    float2* state = (float2*)d_ws;
    float* invn   = (float*)((char*)d_ws + INVN_OFF);
    float* gu     = (float*)((char*)d_ws + GATEU_OFF);
    float* zpart  = (float*)((char*)d_ws + ZPART_OFF);

    qsim::norm_kernel<<<128, 256, 0, stream>>>(x, invn);
    qsim::gateu_kernel<<<1, 64, 0, stream>>>(wts, gu);
    qsim::launch_all(std::make_index_sequence<(std::size_t)qsim::PLAN.ngroups>{},
                     x, gu, state, invn, zpart, stream);
    qsim::out_kernel<<<128, 512, 0, stream>>>(zpart, cw, cb, out);
}

// Round 6
// 488.463 us; speedup vs baseline: 1.4527x; 1.4527x over previous
//
#include <hip/hip_runtime.h>
#include <cmath>
#include <utility>
#include <cstddef>

// ===========================================================================
// Quantum circuit simulation: 16 qubits, 4 StronglyEntanglingLayers.
// CNOTs are GF(2)-linear index permutations -> tracked symbolically in a
// bit-matrix M (zero data movement). Only 64 Rot gates touch amplitudes:
// pairs (p, p^mask), mask = column of M, branch bit = parity(row of M^{-1}
// & p). A constexpr greedy groups gates into passes whose masks fit in a
// 14-dim GF(2) subspace: 6 seeded lane dims (bits 0-5, coalescing) +
// 5 reg dims + 3 WAVE dims -> 5 passes. Cross-wave gates exchange via a
// 64 KiB LDS side-stage (only the side-1 half of each pair is staged;
// side-0 threads compute BOTH pair outputs and write the partner's result
// back). 64 KiB LDS -> 2 WGs/CU possible (16 waves).
// NOTE: NO min-waves clamp in launch_bounds — (512,4) forced VGPR=64 and
// spilled re[]/im[] to scratch (WRITE_SIZE 88->573 MB, 2.7x slower). The
// unclamped build uses 128 VGPR = 16 waves/CU exactly, no spill.
// ===========================================================================

namespace qsim {

constexpr int NQ = 16;
constexpr int NL = 4;
constexpr int NGMAX = 12;   // max groups (passes); greedy yields 5
constexpr int GMAX  = 36;   // max gates per group (max seen: 15)
constexpr int BDIM  = 14;   // 6 lane (seeded) + 5 reg + 3 wave dims
constexpr int CDIM  = 2;    // complement dims (coset bits)

constexpr int parity16(unsigned v) {
    int p = 0;
    for (int k = 0; k < 16; ++k) p ^= (int)((v >> k) & 1u);
    return p;
}

struct PlanT {
    int ngroups;
    int ng[NGMAX];
    unsigned char gl[NGMAX][GMAX];     // layer
    unsigned char gw[NGMAX][GMAX];     // wire
    unsigned short mloc[NGMAX][GMAX];  // 14-bit local mask (0-5 lane, 6-10 reg, 11-13 wave)
    unsigned short rloc[NGMAX][GMAX];  // 14-bit local row-parity vector
    unsigned short grow[NGMAX][GMAX];  // 16-bit global row (for base parity)
    unsigned short V[NGMAX][BDIM];     // basis; V[0..5] == {1,2,4,8,16,32}
    unsigned short U[NGMAX][CDIM];     // complement unit vectors (coset bits)
    unsigned short frow[16];           // rows of final M^{-1}
    unsigned short floc[16];           // frow parities over last group's basis
    bool ok;
};

constexpr PlanT make_plan() {
    PlanT P{};
    P.ok = true;

    // ---- per-gate mask (column of M) and row (row of M^{-1}) ----
    unsigned col[16] = {}, rowv[16] = {};
    for (int b = 0; b < 16; ++b) { col[b] = 1u << b; rowv[b] = 1u << b; }
    unsigned gmask[64] = {}, growg[64] = {};
    unsigned char glay[64] = {}, gwire[64] = {};
    int gi = 0;
    for (int l = 0; l < NL; ++l) {
        for (int w = 0; w < NQ; ++w) {
            const int b = 15 - w;
            gmask[gi] = col[b]; growg[gi] = rowv[b];
            glay[gi] = (unsigned char)l; gwire[gi] = (unsigned char)w; ++gi;
        }
        const int r = (l % (NQ - 1)) + 1;
        for (int w = 0; w < NQ; ++w) {
            const int cb = 15 - w;
            const int tb = 15 - ((w + r) % NQ);
            col[cb] ^= col[tb];      // M' = M * C  (column update)
            rowv[tb] ^= rowv[cb];    // M'^{-1} = C * M^{-1} (row update)
        }
    }
    for (int b = 0; b < 16; ++b) P.frow[b] = (unsigned short)rowv[b];

    // sanity: row_b(M^{-1}) . col_b'(M) == delta
    for (int a = 0; a < 16; ++a)
        for (int b2 = 0; b2 < 16; ++b2)
            if (parity16(rowv[a] & col[b2]) != (a == b2 ? 1 : 0)) P.ok = false;
    // sanity: per gate, row . mask == 1
    for (int i = 0; i < 64; ++i)
        if (parity16(gmask[i] & growg[i]) != 1) P.ok = false;

    // ---- greedy grouping: layer-monotone groups; basis seeded with the 6
    //      low unit bits (lane dims) so global access is always coalesced ----
    bool applied[64] = {};
    int napplied = 0;
    int grp = 0;
    while (napplied < 64) {
        if (grp >= NGMAX) { P.ok = false; break; }
        unsigned B[BDIM] = {}; int piv[BDIM] = {}; int nb = 0;
        // seed: lane dims = bits 0..5 (coalescing guarantee). Seeds are never
        // modified by back-reduction (non-seed pivots are bits >= 6).
        for (int i = 0; i < 6; ++i) { B[i] = 1u << i; piv[i] = i; ++nb; }
        unsigned tmask[GMAX] = {}, trow[GMAX] = {};
        int cnt = 0;
        bool progress = true;
        while (progress) {
            progress = false;
            int lay = -1;
            for (int i = 0; i < 64; ++i)
                if (!applied[i]) { lay = glay[i]; break; }
            if (lay < 0) break;
            for (int w = 15; w >= 0; --w) {   // descending wire scan
                const int idx = lay * 16 + w;
                if (applied[idx]) continue;
                unsigned v = gmask[idx];
                for (int i = 0; i < nb; ++i) if ((v >> piv[i]) & 1u) v ^= B[i];
                if (v != 0u && nb == BDIM) continue;   // doesn't fit
                if (cnt >= GMAX) { P.ok = false; continue; }
                if (v != 0u) {
                    int pb = 0; while (((v >> pb) & 1u) == 0u) ++pb;
                    for (int i = 0; i < nb; ++i) if ((B[i] >> pb) & 1u) B[i] ^= v;
                    B[nb] = v; piv[nb] = pb; ++nb;     // RREF maintained
                }
                P.gl[grp][cnt] = glay[idx];
                P.gw[grp][cnt] = gwire[idx];
                tmask[cnt] = gmask[idx]; trow[cnt] = growg[idx];
                ++cnt;
                applied[idx] = true; ++napplied; progress = true;
            }
        }
        // pad basis to 14 with (reduced) unit vectors, low bits first
        for (int bbit = 0; bbit < 16 && nb < BDIM; ++bbit) {
            unsigned v = 1u << bbit;
            for (int i = 0; i < nb; ++i) if ((v >> piv[i]) & 1u) v ^= B[i];
            if (v != 0u) {
                int pb = 0; while (((v >> pb) & 1u) == 0u) ++pb;
                for (int i = 0; i < nb; ++i) if ((B[i] >> pb) & 1u) B[i] ^= v;
                B[nb] = v; piv[nb] = pb; ++nb;
            }
        }
        if (nb != BDIM) P.ok = false;
        for (int i = 0; i < 6; ++i) if (B[i] != (1u << i)) P.ok = false;

        // provisional coords over basis order (seeds 0-5, insertion 6-13)
        unsigned provml[GMAX] = {};
        for (int g = 0; g < cnt; ++g) {
            unsigned m = tmask[g], ml = 0;
            for (int i = 0; i < BDIM; ++i)
                if ((m >> piv[i]) & 1u) { ml |= 1u << i; m ^= B[i]; }
            if (m != 0u) P.ok = false;
            if (ml == 0u) P.ok = false;
            provml[g] = ml;
        }
        // usage count per non-seed dim; most-used 5 -> reg slots (6-10),
        // least-used 3 -> wave slots (11-13, LDS-exchange gates)
        int usage[BDIM] = {};
        for (int g = 0; g < cnt; ++g)
            for (int i = 6; i < BDIM; ++i)
                if ((provml[g] >> i) & 1u) usage[i]++;
        int ord[8] = {};
        for (int k = 0; k < 8; ++k) ord[k] = 6 + k;
        for (int i = 1; i < 8; ++i) {       // stable insertion sort, desc usage
            int oi = ord[i]; int j = i - 1;
            while (j >= 0 && usage[ord[j]] < usage[oi]) { ord[j+1] = ord[j]; --j; }
            ord[j+1] = oi;
        }
        int slot[BDIM] = {};
        for (int i = 0; i < 6; ++i) slot[i] = i;
        for (int k = 0; k < 8; ++k) slot[ord[k]] = 6 + k;
        // final basis + remapped coords + row parities
        for (int i = 0; i < 6; ++i) P.V[grp][i] = (unsigned short)B[i];
        for (int k = 0; k < 8; ++k) P.V[grp][6 + k] = (unsigned short)B[ord[k]];
        for (int g = 0; g < cnt; ++g) {
            unsigned ml = 0;
            for (int i = 0; i < BDIM; ++i)
                if ((provml[g] >> i) & 1u) ml |= 1u << slot[i];
            P.mloc[grp][g] = (unsigned short)ml;
            unsigned rl = 0;
            for (int s = 0; s < BDIM; ++s)
                rl |= (unsigned)parity16(trow[g] & P.V[grp][s]) << s;
            P.rloc[grp][g] = (unsigned short)rl;
            P.grow[grp][g] = (unsigned short)trow[g];
        }
        // complement unit vectors = non-pivot bits
        int cu = 0;
        for (int bbit = 0; bbit < 16; ++bbit) {
            bool isp = false;
            for (int i = 0; i < BDIM; ++i) if (piv[i] == bbit) isp = true;
            if (!isp) { if (cu < CDIM) P.U[grp][cu] = (unsigned short)(1u << bbit); ++cu; }
        }
        if (cu != CDIM) P.ok = false;
        P.ng[grp] = cnt;
        ++grp;
    }
    P.ngroups = grp;
    // measurement row parities in LAST group's (final-ordered) basis
    for (int q = 0; q < 16; ++q) {
        unsigned rl = 0;
        for (int s = 0; s < BDIM; ++s)
            rl |= (unsigned)parity16(P.frow[q] & P.V[P.ngroups - 1][s]) << s;
        P.floc[q] = (unsigned short)rl;
    }
    return P;
}

constexpr PlanT PLAN = make_plan();
static_assert(PLAN.ok, "constexpr plan construction failed");
static_assert(PLAN.ngroups >= 2 && PLAN.ngroups <= NGMAX, "unexpected group count");

// ---------------------------------------------------------------------------
// device code
// ---------------------------------------------------------------------------

template<int G>
__device__ __forceinline__ unsigned regxor(int r) {
    unsigned rx = 0;
    if (r & 1)  rx ^= PLAN.V[G][6];
    if (r & 2)  rx ^= PLAN.V[G][7];
    if (r & 4)  rx ^= PLAN.V[G][8];
    if (r & 8)  rx ^= PLAN.V[G][9];
    if (r & 16) rx ^= PLAN.V[G][10];
    return rx;
}

template<int G>
__device__ __forceinline__ unsigned wavexor(int wv) {
    unsigned rx = 0;
    if (wv & 1) rx ^= PLAN.V[G][11];
    if (wv & 2) rx ^= PLAN.V[G][12];
    if (wv & 4) rx ^= PLAN.V[G][13];
    return rx;
}

// drop bit sbpos from a 14-bit local index -> 13-bit LDS slot.
// All staged indices have bit sbpos == 1, so the drop is bijective.
__device__ __forceinline__ unsigned compress14(unsigned idx, int sbpos) {
    return (idx & ((1u << sbpos) - 1u)) | ((idx >> (sbpos + 1)) << sbpos);
}

// tfix = (wave<<11) | lane : the thread-fixed local-index bits
template<int G, int g>
__device__ __forceinline__ void apply_gates(float (&re)[32], float (&im)[32],
                                            const float* __restrict__ gu,
                                            unsigned base, int tfix,
                                            float2* tile)
{
    if constexpr (g < PLAN.ng[G]) {
        constexpr int lq = PLAN.gl[G][g];
        constexpr int wq = PLAN.gw[G][g];
        constexpr unsigned ml = PLAN.mloc[G][g];
        constexpr unsigned rl = PLAN.rloc[G][g];
        constexpr unsigned grw = PLAN.grow[G][g];
        constexpr unsigned mlane = ml & 63u;
        constexpr unsigned mreg = (ml >> 6) & 31u;
        constexpr unsigned mwav = ml >> 11;

        const float* up = gu + (lq * 16 + wq) * 8;  // uniform (scalar) loads
        const float U00r = up[0], U00i = up[1];
        const float U01r = up[2], U01i = up[3];
        const float U10r = up[4], U10i = up[5];
        const float U11r = up[6], U11i = up[7];

        // thread-fixed parity from coset base + lane/wave bits
        const int pt = (__popc(grw & base) ^ __popc(rl & (unsigned)tfix)) & 1;
        // coefficients for amps with total parity 0 (E0,F0) and parity 1 (E1,F1)
        const float E0r = pt ? U11r : U00r, E0i = pt ? U11i : U00i;
        const float F0r = pt ? U10r : U01r, F0i = pt ? U10i : U01i;
        const float E1r = pt ? U00r : U11r, E1i = pt ? U00i : U11i;
        const float F1r = pt ? U01r : U10r, F1i = pt ? U01i : U10i;

        if constexpr (mwav != 0u) {
            // cross-wave side-stage through 64 KiB LDS (2^13 slots).
            // sb = lowest wave bit of the mask; side1 threads (bit set) stage
            // their values; side0 threads compute BOTH pair outputs (partner
            // parity = own parity ^ 1, since row.mask == 1) and write the
            // partner's new value back; side1 reads it. Branches are
            // wave-uniform; LDS addresses stay 512B-contiguous per wave.
            constexpr int sbpos = (mwav & 1u) ? 11 : ((mwav & 2u) ? 12 : 13);
            constexpr unsigned sbit = 1u << sbpos;
            const bool side1 = ((unsigned)tfix & sbit) != 0u;
            if (side1) {
                #pragma unroll
                for (int r = 0; r < 32; ++r)
                    tile[compress14((unsigned)(tfix | (r << 6)), sbpos)] =
                        make_float2(re[r], im[r]);
            }
            __syncthreads();
            if (!side1) {
                #pragma unroll
                for (int r = 0; r < 32; ++r) {
                    const unsigned own = (unsigned)(tfix | (r << 6));
                    const unsigned a13 = compress14(own ^ ml, sbpos);
                    const float2 p = tile[a13];
                    const bool cp = (__popc(rl & ((unsigned)r << 6)) & 1) != 0;
                    const float Er = cp ? E1r : E0r, Ei = cp ? E1i : E0i;
                    const float Fr = cp ? F1r : F0r, Fi = cp ? F1i : F0i;
                    const float Gr = cp ? E0r : E1r, Gi = cp ? E0i : E1i;
                    const float Hr = cp ? F0r : F1r, Hi = cp ? F0i : F1i;
                    const float ar = re[r], ai = im[r];
                    re[r] = Er*ar - Ei*ai + Fr*p.x - Fi*p.y;
                    im[r] = Er*ai + Ei*ar + Fr*p.y + Fi*p.x;
                    tile[a13] = make_float2(Gr*p.x - Gi*p.y + Hr*ar - Hi*ai,
                                            Gr*p.y + Gi*p.x + Hr*ai + Hi*ar);
                }
            }
            __syncthreads();
            if (side1) {
                #pragma unroll
                for (int r = 0; r < 32; ++r) {
                    const float2 v =
                        tile[compress14((unsigned)(tfix | (r << 6)), sbpos)];
                    re[r] = v.x; im[r] = v.y;
                }
            }
            __syncthreads();   // WAR: protect slots before next gate stages
        } else if constexpr (mlane == 0u) {
            // pure register pairs (r, r^mreg) within the thread
            constexpr unsigned lb = mreg & (0u - mreg);
            #pragma unroll
            for (int r = 0; r < 32; ++r) {
                if (((unsigned)r & lb) == 0u) {
                    const int k = r ^ (int)mreg;
                    const bool cp = (__popc(rl & ((unsigned)r << 6)) & 1) != 0;
                    const float Ear = cp ? E1r : E0r, Eai = cp ? E1i : E0i;
                    const float Far = cp ? F1r : F0r, Fai = cp ? F1i : F0i;
                    const float Ebr = cp ? E0r : E1r, Ebi = cp ? E0i : E1i;
                    const float Fbr = cp ? F0r : F1r, Fbi = cp ? F0i : F1i;
                    const float ar = re[r], ai = im[r], br = re[k], bi = im[k];
                    re[r] = Ear*ar - Eai*ai + Far*br - Fai*bi;
                    im[r] = Ear*ai + Eai*ar + Far*bi + Fai*br;
                    re[k] = Ebr*br - Ebi*bi + Fbr*ar - Fbi*ai;
                    im[k] = Ebr*bi + Ebi*br + Fbr*ai + Fbi*ar;
                }
            }
        } else if constexpr (mreg == 0u) {
            // cross-lane only: partner = same reg on lane^mlane
            #pragma unroll
            for (int r = 0; r < 32; ++r) {
                const float pr = __shfl_xor(re[r], (int)mlane, 64);
                const float pi = __shfl_xor(im[r], (int)mlane, 64);
                const bool cp = (__popc(rl & ((unsigned)r << 6)) & 1) != 0;
                const float Er = cp ? E1r : E0r, Ei = cp ? E1i : E0i;
                const float Fr = cp ? F1r : F0r, Fi = cp ? F1i : F0i;
                const float ar = re[r], ai = im[r];
                re[r] = Er*ar - Ei*ai + Fr*pr - Fi*pi;
                im[r] = Er*ai + Ei*ar + Fr*pi + Fi*pr;
            }
        } else {
            // mixed lane+reg: partner = reg r^mreg on lane^mlane; prefetch
            // both directions of each reg pair via shfl BEFORE writing either.
            constexpr unsigned lb = mreg & (0u - mreg);
            #pragma unroll
            for (int r = 0; r < 32; ++r) {
                if (((unsigned)r & lb) == 0u) {
                    const int k = r ^ (int)mreg;
                    const float prr = __shfl_xor(re[k], (int)mlane, 64);
                    const float pri = __shfl_xor(im[k], (int)mlane, 64);
                    const float pkr = __shfl_xor(re[r], (int)mlane, 64);
                    const float pki = __shfl_xor(im[r], (int)mlane, 64);
                    const bool cpr = (__popc(rl & ((unsigned)r << 6)) & 1) != 0;
                    const bool cpk = (__popc(rl & ((unsigned)k << 6)) & 1) != 0;
                    {
                        const float Er = cpr ? E1r : E0r, Ei = cpr ? E1i : E0i;
                        const float Fr = cpr ? F1r : F0r, Fi = cpr ? F1i : F0i;
                        const float ar = re[r], ai = im[r];
                        re[r] = Er*ar - Ei*ai + Fr*prr - Fi*pri;
                        im[r] = Er*ai + Ei*ar + Fr*pri + Fi*prr;
                    }
                    {
                        const float Er = cpk ? E1r : E0r, Ei = cpk ? E1i : E0i;
                        const float Fr = cpk ? F1r : F0r, Fi = cpk ? F1i : F0i;
                        const float ar = re[k], ai = im[k];
                        re[k] = Er*ar - Ei*ai + Fr*pkr - Fi*pki;
                        im[k] = Er*ai + Ei*ar + Fr*pki + Fi*pkr;
                    }
                }
            }
        }
        apply_gates<G, g + 1>(re, im, gu, base, tfix, tile);
    }
}

// one 512-thread WG = one (batch, coset) tile of 2^14 amplitudes,
// 32 complex/thread; 8 waves; cross-wave gates via 64 KiB LDS side-stage.
// NO min-waves clamp: compiler's natural 128 VGPR = 16 waves/CU, no spill.
template<int G, bool FIRST, bool LAST>
__global__ __launch_bounds__(512)
void pass_kernel(const float* __restrict__ x,
                 const float* __restrict__ gu,
                 float2* __restrict__ state,
                 const float* __restrict__ invn,
                 float* __restrict__ zpart)
{
    __shared__ float2 tile[1 << 13];   // 64 KiB side-stage
    const int lane = (int)(threadIdx.x & 63u);
    const int wave = (int)(threadIdx.x >> 6);
    const int batch = (int)blockIdx.x >> 2;
    const unsigned coset = (unsigned)blockIdx.x & 3u;

    unsigned base = 0;
    if (coset & 1u) base ^= PLAN.U[G][0];
    if (coset & 2u) base ^= PLAN.U[G][1];
    // lane dims are literal bits 0-5 -> contiguous 64 x float2 per wave
    const unsigned pfix = base ^ (unsigned)lane ^ wavexor<G>(wave);
    const int tfix = (wave << 11) | lane;
    const int boff = batch << 16;

    float re[32], im[32];
    if constexpr (FIRST) {
        const float inv = invn[batch];
        #pragma unroll
        for (int r = 0; r < 32; ++r) {
            re[r] = x[boff + (int)(pfix ^ regxor<G>(r))] * inv;
            im[r] = 0.f;
        }
    } else {
        #pragma unroll
        for (int r = 0; r < 32; ++r) {
            const float2 v = state[boff + (int)(pfix ^ regxor<G>(r))];
            re[r] = v.x; im[r] = v.y;
        }
    }

    apply_gates<G, 0>(re, im, gu, base, tfix, tile);

    if constexpr (LAST) {
        // <Z_q> partials: sign = parity(frow[q] & p)
        float acc[16];
        #pragma unroll
        for (int q = 0; q < 16; ++q) acc[q] = 0.f;
        #pragma unroll
        for (int r = 0; r < 32; ++r) {
            const float p = re[r]*re[r] + im[r]*im[r];
            #pragma unroll
            for (int q = 0; q < 16; ++q) {
                const bool sp = (__popc((unsigned)PLAN.floc[q] & ((unsigned)r << 6)) & 1) != 0;
                acc[q] += sp ? -p : p;
            }
        }
        const int W = (int)blockIdx.x * 8 + wave;
        #pragma unroll
        for (int q = 0; q < 16; ++q) {
            const int fl = (__popc((unsigned)PLAN.frow[q] & base) ^
                            __popc((unsigned)PLAN.floc[q] & (unsigned)tfix)) & 1;
            float v = fl ? -acc[q] : acc[q];
            #pragma unroll
            for (int o = 32; o; o >>= 1) v += __shfl_xor(v, o, 64);
            if (lane == 0) zpart[W * 16 + q] = v;
        }
    } else {
        #pragma unroll
        for (int r = 0; r < 32; ++r)
            state[boff + (int)(pfix ^ regxor<G>(r))] = make_float2(re[r], im[r]);
    }
}

__global__ __launch_bounds__(256)
void norm_kernel(const float* __restrict__ x, float* __restrict__ invn)
{
    const int b = (int)blockIdx.x;
    const float4* xv = reinterpret_cast<const float4*>(x + ((size_t)b << 16));
    float s = 0.f;
    for (int i = (int)threadIdx.x; i < 16384; i += 256) {
        const float4 v = xv[i];
        s += v.x*v.x + v.y*v.y + v.z*v.z + v.w*v.w;
    }
    #pragma unroll
    for (int o = 32; o; o >>= 1) s += __shfl_xor(s, o, 64);
    __shared__ float partial[4];
    if ((threadIdx.x & 63u) == 0u) partial[threadIdx.x >> 6] = s;
    __syncthreads();
    if (threadIdx.x == 0) {
        const float t = partial[0] + partial[1] + partial[2] + partial[3];
        invn[b] = 1.0f / sqrtf(t);
    }
}

// precompute the 64 Rot matrices (PennyLane Rot = RZ(om) RY(th) RZ(phi))
__global__ void gateu_kernel(const float* __restrict__ wts, float* __restrict__ gu)
{
    const int i = (int)threadIdx.x;  // gate index l*16+w
    if (i < 64) {
        const float phi = wts[i*3+0], th = wts[i*3+1], om = wts[i*3+2];
        float sh, ch; sincosf(0.5f * th, &sh, &ch);
        float sap, cap; sincosf(0.5f * (phi + om), &sap, &cap);
        float sam, cam; sincosf(0.5f * (phi - om), &sam, &cam);
        gu[i*8+0] =  cap*ch;  gu[i*8+1] = -sap*ch;   // U00 = e^{-i(phi+om)/2} c
        gu[i*8+2] = -cam*sh;  gu[i*8+3] = -sam*sh;   // U01 = -e^{ i(phi-om)/2} s
        gu[i*8+4] =  cam*sh;  gu[i*8+5] = -sam*sh;   // U10 =  e^{-i(phi-om)/2} s
        gu[i*8+6] =  cap*ch;  gu[i*8+7] =  sap*ch;   // U11 =  e^{ i(phi+om)/2} c
    }
}

__global__ __launch_bounds__(512)
void out_kernel(const float* __restrict__ zpart, const float* __restrict__ cw,
                const float* __restrict__ cb, float* __restrict__ out)
{
    const int b = (int)blockIdx.x;
    const int q = (int)(threadIdx.x >> 5);
    const int c = (int)(threadIdx.x & 31u);
    float v = zpart[(size_t)(((b << 5) | c) * 16 + q)];
    #pragma unroll
    for (int o = 16; o; o >>= 1) v += __shfl_xor(v, o, 32);
    __shared__ float z[16];
    if (c == 0) z[q] = v;
    __syncthreads();
    if (threadIdx.x < 2) {
        const int o = (int)threadIdx.x;
        float acc = cb[o];
        #pragma unroll
        for (int w = 0; w < 16; ++w) acc += cw[o * 16 + w] * z[15 - w];
        out[b * 2 + o] = acc;
    }
}

__global__ void sentinel_kernel(float* out)
{
    if (threadIdx.x < 256) out[threadIdx.x] = -12345.0f;  // ws too small marker
}

template<int I>
static void launch_one(const float* x, const float* gu, float2* state,
                       const float* invn, float* zpart, hipStream_t s)
{
    pass_kernel<I, I == 0, I == PLAN.ngroups - 1>
        <<<512, 512, 0, s>>>(x, gu, state, invn, zpart);
}

template<std::size_t... I>
static void launch_all(std::index_sequence<I...>, const float* x, const float* gu,
                       float2* state, const float* invn, float* zpart, hipStream_t s)
{
    (launch_one<(int)I>(x, gu, state, invn, zpart, s), ...);
}

} // namespace qsim

extern "C" void kernel_launch(void* const* d_in, const int* in_sizes, int n_in,
                              void* d_out, int out_size, void* d_ws, size_t ws_size,
                              hipStream_t stream)
{
    (void)in_sizes; (void)n_in; (void)out_size;
    const float* x   = (const float*)d_in[0];   // (128,256,256) f32
    const float* wts = (const float*)d_in[1];   // (4,16,3) f32
    const float* cw  = (const float*)d_in[2];   // (2,16) f32
    const float* cb  = (const float*)d_in[3];   // (2,) f32
    float* out = (float*)d_out;                 // (128,2) f32

    constexpr size_t STATE_BYTES = (size_t)128 * 65536 * sizeof(float2); // 64 MiB
    constexpr size_t INVN_OFF  = STATE_BYTES;                  // 128 floats
    constexpr size_t GATEU_OFF = STATE_BYTES + 1024;           // 64*8 floats
    constexpr size_t ZPART_OFF = STATE_BYTES + 1024 + 4096;    // 4096*16 floats
    constexpr size_t NEED = ZPART_OFF + (size_t)4096 * 16 * sizeof(float);

    if (ws_size < NEED) {
        qsim::sentinel_kernel<<<1, 256, 0, stream>>>(out);
        return;
    }

    float2* state = (float2*)d_ws;
    float* invn   = (float*)((char*)d_ws + INVN_OFF);
    float* gu     = (float*)((char*)d_ws + GATEU_OFF);
    float* zpart  = (float*)((char*)d_ws + ZPART_OFF);

    qsim::norm_kernel<<<128, 256, 0, stream>>>(x, invn);
    qsim::gateu_kernel<<<1, 64, 0, stream>>>(wts, gu);
    qsim::launch_all(std::make_index_sequence<(std::size_t)qsim::PLAN.ngroups>{},
                     x, gu, state, invn, zpart, stream);
    qsim::out_kernel<<<128, 512, 0, stream>>>(zpart, cw, cb, out);
}

// Round 7
// 317.378 us; speedup vs baseline: 2.2358x; 1.5391x over previous
//
#include <hip/hip_runtime.h>
#include <cmath>
#include <utility>
#include <cstddef>

// ===========================================================================
// Quantum circuit simulation: 16 qubits, 4 StronglyEntanglingLayers.
// CNOTs are GF(2)-linear index permutations -> tracked symbolically in a
// bit-matrix M (zero data movement). Only 64 Rot gates touch amplitudes:
// pairs (p, p^mask), mask = column of M, branch bit = parity(row of M^{-1}
// & p). A constexpr greedy groups gates into passes whose masks fit a
// 13-dim GF(2) subspace (6 seeded lane dims for coalescing + 7 free).
// NEW in this round: amplitudes live in a 64 KiB LDS tile (2^13 float2)
// per 512-thread WG instead of registers. Empirical law from rounds 2-6:
// waves/SIMD = floor(256/VGPR); the old reg-resident design (128 VGPR)
// was pinned at 8 waves/CU. LDS-resident gates need ~40-60 VGPR, and
// __launch_bounds__(512,4) clamps to 64 -> 2 WGs/CU (16 waves), giving
// 2x latency hiding + load/compute overlap across co-resident WGs.
// Gate paths: mask<64 -> own-slot + shfl_xor partner (no barrier between
// consecutive such gates); mask>=64 -> LDS pair path with highest-bit
// index expansion (conflict-free b64). Sign trick (U11=conj U00,
// U10=-conj U01) => 4 xor + 16 FMA per pair, 4 coeff regs.
// ===========================================================================

namespace qsim {

constexpr int NQ = 16;
constexpr int NL = 4;
constexpr int NGMAX = 12;   // max groups; greedy yields 6 at BDIM=13
constexpr int GMAX  = 36;   // max gates per group (max seen: 15)
constexpr int BDIM  = 13;   // 6 lane (seeded) + 3 tid-mid + 4 j-hi dims
constexpr int CDIM  = 3;    // complement dims (coset bits)

constexpr int parity16(unsigned v) {
    int p = 0;
    for (int k = 0; k < 16; ++k) p ^= (int)((v >> k) & 1u);
    return p;
}
constexpr int topbit(unsigned v) {
    int b = -1;
    for (int k = 0; k < 16; ++k) if ((v >> k) & 1u) b = k;
    return b;
}

struct PlanT {
    int ngroups;
    int ng[NGMAX];
    unsigned char gl[NGMAX][GMAX];     // layer
    unsigned char gw[NGMAX][GMAX];     // wire
    unsigned short mloc[NGMAX][GMAX];  // 13-bit local mask
    unsigned short rloc[NGMAX][GMAX];  // 13-bit local row-parity vector
    unsigned short grow[NGMAX][GMAX];  // 16-bit global row (base parity)
    unsigned short V[NGMAX][BDIM];     // basis; V[0..5] == {1,2,4,8,16,32}
    unsigned short U[NGMAX][CDIM];     // complement unit vectors
    unsigned short frow[16];           // rows of final M^{-1}
    unsigned short floc[16];           // frow parities over last basis
    bool ok;
};

constexpr PlanT make_plan() {
    PlanT P{};
    P.ok = true;

    unsigned col[16] = {}, rowv[16] = {};
    for (int b = 0; b < 16; ++b) { col[b] = 1u << b; rowv[b] = 1u << b; }
    unsigned gmask[64] = {}, growg[64] = {};
    unsigned char glay[64] = {}, gwire[64] = {};
    int gi = 0;
    for (int l = 0; l < NL; ++l) {
        for (int w = 0; w < NQ; ++w) {
            const int b = 15 - w;
            gmask[gi] = col[b]; growg[gi] = rowv[b];
            glay[gi] = (unsigned char)l; gwire[gi] = (unsigned char)w; ++gi;
        }
        const int r = (l % (NQ - 1)) + 1;
        for (int w = 0; w < NQ; ++w) {
            const int cb = 15 - w;
            const int tb = 15 - ((w + r) % NQ);
            col[cb] ^= col[tb];      // M' = M * C
            rowv[tb] ^= rowv[cb];    // M'^{-1} = C * M^{-1}
        }
    }
    for (int b = 0; b < 16; ++b) P.frow[b] = (unsigned short)rowv[b];

    for (int a = 0; a < 16; ++a)
        for (int b2 = 0; b2 < 16; ++b2)
            if (parity16(rowv[a] & col[b2]) != (a == b2 ? 1 : 0)) P.ok = false;
    for (int i = 0; i < 64; ++i)
        if (parity16(gmask[i] & growg[i]) != 1) P.ok = false;

    bool applied[64] = {};
    int napplied = 0, grp = 0;
    while (napplied < 64) {
        if (grp >= NGMAX) { P.ok = false; break; }
        unsigned B[BDIM] = {}; int piv[BDIM] = {}; int nb = 0;
        for (int i = 0; i < 6; ++i) { B[i] = 1u << i; piv[i] = i; ++nb; }
        unsigned tmask[GMAX] = {}, trow[GMAX] = {};
        int cnt = 0;
        bool progress = true;
        while (progress) {
            progress = false;
            int lay = -1;
            for (int i = 0; i < 64; ++i)
                if (!applied[i]) { lay = glay[i]; break; }
            if (lay < 0) break;
            for (int w = 15; w >= 0; --w) {
                const int idx = lay * 16 + w;
                if (applied[idx]) continue;
                unsigned v = gmask[idx];
                for (int i = 0; i < nb; ++i) if ((v >> piv[i]) & 1u) v ^= B[i];
                if (v != 0u && nb == BDIM) continue;
                if (cnt >= GMAX) { P.ok = false; continue; }
                if (v != 0u) {
                    int pb = 0; while (((v >> pb) & 1u) == 0u) ++pb;
                    for (int i = 0; i < nb; ++i) if ((B[i] >> pb) & 1u) B[i] ^= v;
                    B[nb] = v; piv[nb] = pb; ++nb;
                }
                P.gl[grp][cnt] = glay[idx];
                P.gw[grp][cnt] = gwire[idx];
                tmask[cnt] = gmask[idx]; trow[cnt] = growg[idx];
                ++cnt;
                applied[idx] = true; ++napplied; progress = true;
            }
        }
        for (int bbit = 0; bbit < 16 && nb < BDIM; ++bbit) {
            unsigned v = 1u << bbit;
            for (int i = 0; i < nb; ++i) if ((v >> piv[i]) & 1u) v ^= B[i];
            if (v != 0u) {
                int pb = 0; while (((v >> pb) & 1u) == 0u) ++pb;
                for (int i = 0; i < nb; ++i) if ((B[i] >> pb) & 1u) B[i] ^= v;
                B[nb] = v; piv[nb] = pb; ++nb;
            }
        }
        if (nb != BDIM) P.ok = false;
        // value sort: seeds (1..32) stay in slots 0-5 (non-seeds >= 64)
        for (int i = 1; i < BDIM; ++i) {
            unsigned bv = B[i]; int pv = piv[i]; int j = i - 1;
            while (j >= 0 && B[j] > bv) { B[j+1] = B[j]; piv[j+1] = piv[j]; --j; }
            B[j+1] = bv; piv[j+1] = pv;
        }
        for (int i = 0; i < 6; ++i) if (B[i] != (1u << i)) P.ok = false;
        for (int i = 0; i < BDIM; ++i) P.V[grp][i] = (unsigned short)B[i];
        int cu = 0;
        for (int bbit = 0; bbit < 16; ++bbit) {
            bool isp = false;
            for (int i = 0; i < BDIM; ++i) if (piv[i] == bbit) isp = true;
            if (!isp) { if (cu < CDIM) P.U[grp][cu] = (unsigned short)(1u << bbit); ++cu; }
        }
        if (cu != CDIM) P.ok = false;
        for (int g = 0; g < cnt; ++g) {
            unsigned m = tmask[g], ml = 0;
            for (int i = 0; i < BDIM; ++i)
                if ((m >> piv[i]) & 1u) { ml |= 1u << i; m ^= B[i]; }
            if (m != 0u) P.ok = false;
            if (ml == 0u) P.ok = false;
            P.mloc[grp][g] = (unsigned short)ml;
            unsigned rl = 0;
            for (int i = 0; i < BDIM; ++i)
                rl |= (unsigned)parity16(trow[g] & B[i]) << i;
            P.rloc[grp][g] = (unsigned short)rl;
            P.grow[grp][g] = (unsigned short)trow[g];
        }
        P.ng[grp] = cnt;
        ++grp;
    }
    P.ngroups = grp;
    for (int q = 0; q < 16; ++q) {
        unsigned rl = 0;
        for (int s = 0; s < BDIM; ++s)
            rl |= (unsigned)parity16(P.frow[q] & P.V[P.ngroups - 1][s]) << s;
        P.floc[q] = (unsigned short)rl;
    }
    return P;
}

constexpr PlanT PLAN = make_plan();
static_assert(PLAN.ok, "constexpr plan construction failed");
static_assert(PLAN.ngroups >= 2 && PLAN.ngroups <= NGMAX, "unexpected group count");

// ---------------------------------------------------------------------------
// device code
// ---------------------------------------------------------------------------

__device__ __forceinline__ float xsgn(float v, unsigned sb) {
    return __uint_as_float(__float_as_uint(v) ^ sb);
}

template<int G>
__device__ __forceinline__ unsigned vmid(int tid) {   // tid bits 6..8
    unsigned rx = 0;
    if (tid & 64)  rx ^= PLAN.V[G][6];
    if (tid & 128) rx ^= PLAN.V[G][7];
    if (tid & 256) rx ^= PLAN.V[G][8];
    return rx;
}
template<int G>
__device__ __forceinline__ unsigned vhi(int j) {      // L bits 9..12
    unsigned rx = 0;
    if (j & 1) rx ^= PLAN.V[G][9];
    if (j & 2) rx ^= PLAN.V[G][10];
    if (j & 4) rx ^= PLAN.V[G][11];
    if (j & 8) rx ^= PLAN.V[G][12];
    return rx;
}

// Gate coefficients: U00=(u0r,u0i), U01=(u1r,u1i); U11=conj(U00),
// U10=-conj(U01). Slot with branch parity p uses sign s=(p?-1:+1):
//   new = (u0r, s*u0i)*own + (s*u1r, u1i)*partner   (complex mul)
template<int G, int g>
__device__ __forceinline__ void apply_gates(float2* tile,
                                            const float* __restrict__ gu,
                                            unsigned base, int tid)
{
    if constexpr (g < PLAN.ng[G]) {
        constexpr unsigned ml  = PLAN.mloc[G][g];
        constexpr unsigned rl  = PLAN.rloc[G][g];
        constexpr unsigned grw = PLAN.grow[G][g];
        constexpr int gidx = PLAN.gl[G][g] * 16 + PLAN.gw[G][g];

        const float* up = gu + gidx * 8;  // uniform loads
        const float u0r = up[0], u0i = up[1], u1r = up[2], u1i = up[3];
        const int pgb = __popc(grw & base) & 1;

        if constexpr (ml < 64u) {
            // lane-only mask: own slot + shfl partner; no cross-wave traffic
            const int prt = (pgb ^ __popc(rl & (unsigned)tid)) & 1;
            #pragma unroll
            for (int j = 0; j < 16; ++j) {
                const int L = (j << 9) | tid;
                const float2 a = tile[L];
                const float bx = __shfl_xor(a.x, (int)ml, 64);
                const float by = __shfl_xor(a.y, (int)ml, 64);
                const int p = prt ^ (__popc(rl & ((unsigned)j << 9)) & 1); // folds
                const unsigned sb = (unsigned)p << 31;
                const float say = xsgn(a.y, sb), sax = xsgn(a.x, sb);
                const float sbx = xsgn(bx, sb),  sby = xsgn(by, sb);
                float2 o;
                o.x = u0r*a.x - u0i*say + u1r*sbx - u1i*by;
                o.y = u0r*a.y + u0i*sax + u1r*sby + u1i*bx;
                tile[L] = o;
            }
        } else {
            // pair path: expand 12-bit c by inserting 0 at highest mask bit
            // (hb >= 6 since ml >= 64) -> low 6 bits stay = lane: conflict-free
            constexpr int hb = topbit(ml);
            #pragma unroll
            for (int j = 0; j < 8; ++j) {
                const unsigned c = ((unsigned)j << 9) | (unsigned)tid;
                const unsigned i = ((c >> hb) << (hb + 1)) | (c & ((1u << hb) - 1u));
                const unsigned k = i ^ ml;
                const float2 a = tile[i];
                const float2 b = tile[k];
                const int p = (pgb ^ __popc(rl & i)) & 1;
                const unsigned sb = (unsigned)p << 31;
                const float say = xsgn(a.y, sb), sax = xsgn(a.x, sb);
                const float sbx = xsgn(b.x, sb), sby = xsgn(b.y, sb);
                float2 oi, ok;
                oi.x = u0r*a.x - u0i*say + u1r*sbx - u1i*b.y;
                oi.y = u0r*a.y + u0i*sax + u1r*sby + u1i*b.x;
                // partner parity = p^1 (row.mask==1) -> sign flipped
                ok.x = u0r*b.x + u0i*sby - u1r*sax - u1i*a.y;
                ok.y = u0r*b.y - u0i*sbx - u1r*say + u1i*a.x;
                tile[i] = oi; tile[k] = ok;
            }
        }
        // barrier unless this gate was lane-only AND the next consumer only
        // reads own slots (next lane gate, or the store/measure epilogue)
        constexpr bool cur_lane  = (ml < 64u);
        constexpr bool next_lane = (g + 1 < PLAN.ng[G]) &&
                                   (PLAN.mloc[G][g + 1] < 64u);
        constexpr bool last_gate = (g + 1 >= PLAN.ng[G]);
        if constexpr (!(cur_lane && (next_lane || last_gate))) __syncthreads();
        apply_gates<G, g + 1>(tile, gu, base, tid);
    }
}

// one 512-thread WG = one (batch, coset) tile of 2^13 amplitudes in LDS.
// launch_bounds(512,4) clamps VGPR<=64 (LDS-resident gates fit) so
// 2 WGs/CU co-reside: 16 waves, load/compute overlap between WGs.
template<int G, bool FIRST, bool LAST>
__global__ __launch_bounds__(512, 4)
void pass_kernel(const float* __restrict__ x,
                 const float* __restrict__ gu,
                 float2* __restrict__ state,
                 const float* __restrict__ invn,
                 float* __restrict__ zpart)
{
    __shared__ float2 tile[1 << 13];   // 64 KiB
    const int tid = (int)threadIdx.x;
    const int batch = (int)blockIdx.x >> 3;
    const unsigned coset = (unsigned)blockIdx.x & 7u;

    unsigned base = 0;
    if (coset & 1u) base ^= PLAN.U[G][0];
    if (coset & 2u) base ^= PLAN.U[G][1];
    if (coset & 4u) base ^= PLAN.U[G][2];
    // lane dims are literal bits 0-5 -> 512B-contiguous per wave
    const unsigned gbt = base ^ (unsigned)(tid & 63) ^ vmid<G>(tid);
    const int boff = batch << 16;

    if constexpr (FIRST) {
        const float inv = invn[batch];
        #pragma unroll
        for (int j = 0; j < 16; ++j)
            tile[(j << 9) | tid] =
                make_float2(x[boff + (int)(gbt ^ vhi<G>(j))] * inv, 0.f);
    } else {
        #pragma unroll
        for (int j = 0; j < 16; ++j)
            tile[(j << 9) | tid] = state[boff + (int)(gbt ^ vhi<G>(j))];
    }
    // load writes own slots; skip barrier if first gate is lane-only
    if constexpr (!(PLAN.ng[G] > 0 && PLAN.mloc[G][0] < 64u)) __syncthreads();

    apply_gates<G, 0>(tile, gu, base, tid);

    if constexpr (LAST) {
        // <Z_q> partials; sign(slot L) = parity(frow[q]&base) ^ parity(floc[q]&L)
        unsigned sbits = 0;
        #pragma unroll
        for (int q = 0; q < 16; ++q) {
            const int s0 = (__popc((unsigned)PLAN.frow[q] & base)
                          + __popc((unsigned)PLAN.floc[q] & (unsigned)tid)) & 1;
            sbits |= (unsigned)s0 << q;
        }
        const int wave = tid >> 6, lane = tid & 63;
        const int W = (int)blockIdx.x * 8 + wave;
        #pragma unroll
        for (int h = 0; h < 2; ++h) {          // two halves of 8 q's (VGPR)
            float acc[8] = {0,0,0,0,0,0,0,0};
            #pragma unroll
            for (int j = 0; j < 16; ++j) {
                const float2 a = tile[(j << 9) | tid];
                const float pr = a.x*a.x + a.y*a.y;
                #pragma unroll
                for (int q8 = 0; q8 < 8; ++q8) {
                    const int q = h * 8 + q8;
                    const int s = (int)((sbits >> q) & 1u) ^
                        (__popc((unsigned)PLAN.floc[q] & ((unsigned)j << 9)) & 1);
                    acc[q8] += s ? -pr : pr;
                }
            }
            #pragma unroll
            for (int q8 = 0; q8 < 8; ++q8) {
                float v = acc[q8];
                #pragma unroll
                for (int o = 32; o; o >>= 1) v += __shfl_xor(v, o, 64);
                if (lane == 0) zpart[W * 16 + h * 8 + q8] = v;
            }
        }
    } else {
        #pragma unroll
        for (int j = 0; j < 16; ++j)
            state[boff + (int)(gbt ^ vhi<G>(j))] = tile[(j << 9) | tid];
    }
}

__global__ __launch_bounds__(256)
void norm_kernel(const float* __restrict__ x, float* __restrict__ invn)
{
    const int b = (int)blockIdx.x;
    const float4* xv = reinterpret_cast<const float4*>(x + ((size_t)b << 16));
    float s = 0.f;
    for (int i = (int)threadIdx.x; i < 16384; i += 256) {
        const float4 v = xv[i];
        s += v.x*v.x + v.y*v.y + v.z*v.z + v.w*v.w;
    }
    #pragma unroll
    for (int o = 32; o; o >>= 1) s += __shfl_xor(s, o, 64);
    __shared__ float partial[4];
    if ((threadIdx.x & 63u) == 0u) partial[threadIdx.x >> 6] = s;
    __syncthreads();
    if (threadIdx.x == 0) {
        const float t = partial[0] + partial[1] + partial[2] + partial[3];
        invn[b] = 1.0f / sqrtf(t);
    }
}

// precompute the 64 Rot matrices (PennyLane Rot = RZ(om) RY(th) RZ(phi))
__global__ void gateu_kernel(const float* __restrict__ wts, float* __restrict__ gu)
{
    const int i = (int)threadIdx.x;  // gate index l*16+w
    if (i < 64) {
        const float phi = wts[i*3+0], th = wts[i*3+1], om = wts[i*3+2];
        float sh, ch; sincosf(0.5f * th, &sh, &ch);
        float sap, cap; sincosf(0.5f * (phi + om), &sap, &cap);
        float sam, cam; sincosf(0.5f * (phi - om), &sam, &cam);
        gu[i*8+0] =  cap*ch;  gu[i*8+1] = -sap*ch;   // U00
        gu[i*8+2] = -cam*sh;  gu[i*8+3] = -sam*sh;   // U01
        gu[i*8+4] =  cam*sh;  gu[i*8+5] = -sam*sh;   // U10 (unused on device)
        gu[i*8+6] =  cap*ch;  gu[i*8+7] =  sap*ch;   // U11 (unused on device)
    }
}

__global__ __launch_bounds__(1024)
void out_kernel(const float* __restrict__ zpart, const float* __restrict__ cw,
                const float* __restrict__ cb, float* __restrict__ out)
{
    const int b = (int)blockIdx.x;
    const int q = (int)(threadIdx.x >> 6);   // one wave per qubit-bit
    const int c = (int)(threadIdx.x & 63u);  // 8 cosets x 8 waves
    float v = zpart[(size_t)(((b << 6) | c) * 16 + q)];
    #pragma unroll
    for (int o = 32; o; o >>= 1) v += __shfl_xor(v, o, 64);
    __shared__ float z[16];
    if (c == 0) z[q] = v;
    __syncthreads();
    if (threadIdx.x < 2) {
        const int o = (int)threadIdx.x;
        float acc = cb[o];
        #pragma unroll
        for (int w = 0; w < 16; ++w) acc += cw[o * 16 + w] * z[15 - w];
        out[b * 2 + o] = acc;
    }
}

__global__ void sentinel_kernel(float* out)
{
    if (threadIdx.x < 256) out[threadIdx.x] = -12345.0f;  // ws too small marker
}

template<int I>
static void launch_one(const float* x, const float* gu, float2* state,
                       const float* invn, float* zpart, hipStream_t s)
{
    pass_kernel<I, I == 0, I == PLAN.ngroups - 1>
        <<<1024, 512, 0, s>>>(x, gu, state, invn, zpart);
}

template<std::size_t... I>
static void launch_all(std::index_sequence<I...>, const float* x, const float* gu,
                       float2* state, const float* invn, float* zpart, hipStream_t s)
{
    (launch_one<(int)I>(x, gu, state, invn, zpart, s), ...);
}

} // namespace qsim

extern "C" void kernel_launch(void* const* d_in, const int* in_sizes, int n_in,
                              void* d_out, int out_size, void* d_ws, size_t ws_size,
                              hipStream_t stream)
{
    (void)in_sizes; (void)n_in; (void)out_size;
    const float* x   = (const float*)d_in[0];   // (128,256,256) f32
    const float* wts = (const float*)d_in[1];   // (4,16,3) f32
    const float* cw  = (const float*)d_in[2];   // (2,16) f32
    const float* cb  = (const float*)d_in[3];   // (2,) f32
    float* out = (float*)d_out;                 // (128,2) f32

    constexpr size_t STATE_BYTES = (size_t)128 * 65536 * sizeof(float2); // 64 MiB
    constexpr size_t INVN_OFF  = STATE_BYTES;                  // 128 floats
    constexpr size_t GATEU_OFF = STATE_BYTES + 1024;           // 64*8 floats
    constexpr size_t ZPART_OFF = STATE_BYTES + 1024 + 4096;
    constexpr size_t ZPART_BYTES = (size_t)1024 * 8 * 16 * sizeof(float); // 512 KiB
    constexpr size_t NEED = ZPART_OFF + ZPART_BYTES;

    if (ws_size < NEED) {
        qsim::sentinel_kernel<<<1, 256, 0, stream>>>(out);
        return;
    }

    float2* state = (float2*)d_ws;
    float* invn   = (float*)((char*)d_ws + INVN_OFF);
    float* gu     = (float*)((char*)d_ws + GATEU_OFF);
    float* zpart  = (float*)((char*)d_ws + ZPART_OFF);

    qsim::norm_kernel<<<128, 256, 0, stream>>>(x, invn);
    qsim::gateu_kernel<<<1, 64, 0, stream>>>(wts, gu);
    qsim::launch_all(std::make_index_sequence<(std::size_t)qsim::PLAN.ngroups>{},
                     x, gu, state, invn, zpart, stream);
    qsim::out_kernel<<<128, 1024, 0, stream>>>(zpart, cw, cb, out);
}

// Round 8
// 283.797 us; speedup vs baseline: 2.5003x; 1.1183x over previous
//
#include <hip/hip_runtime.h>
#include <cmath>
#include <utility>
#include <cstddef>

// ===========================================================================
// Quantum circuit simulation: 16 qubits, 4 StronglyEntanglingLayers.
// CNOTs are GF(2)-linear index permutations -> tracked symbolically in a
// bit-matrix M (zero data movement). Only 64 Rot gates touch amplitudes:
// pairs (p, p^mask), mask = column of M, branch bit = parity(row of M^{-1}
// & p). A constexpr greedy groups gates into passes whose masks fit a
// 13-dim GF(2) subspace (6 seeded lane dims for coalescing + 7 free).
// Amplitudes live in a 64 KiB LDS tile (2^13 float2) per WG.
// ROUND 8 CHANGE: WG = 1024 threads (16 waves), 8 slots/thread (was 512
// threads x 16 slots). LDS still allows 2 WGs/CU -> 32 waves/CU = the
// hardware max (was 16), doubling latency hiding, which round 7 showed
// was the limiter (occupancy 35%, VALU 56%, HBM 18%). VGPR natural ~52
// <= 64 clamp from __launch_bounds__(1024,8) -> no spill (round-5 lesson:
// only clamp when natural usage fits).
// Gate paths: mask<64 -> own-slot + shfl_xor partner (no barrier between
// consecutive such gates); mask>=64 -> LDS pair path with highest-bit
// index expansion (conflict-free b64). Sign trick (U11=conj U00,
// U10=-conj U01) => 4 xor + 16 FMA per pair, 4 coeff regs.
// ===========================================================================

namespace qsim {

constexpr int NQ = 16;
constexpr int NL = 4;
constexpr int NGMAX = 12;   // max groups; greedy yields 6 at BDIM=13
constexpr int GMAX  = 36;   // max gates per group (max seen: 15)
constexpr int BDIM  = 13;   // 6 lane (seeded) + 4 tid-mid + 3 j-hi dims
constexpr int CDIM  = 3;    // complement dims (coset bits)

constexpr int parity16(unsigned v) {
    int p = 0;
    for (int k = 0; k < 16; ++k) p ^= (int)((v >> k) & 1u);
    return p;
}
constexpr int topbit(unsigned v) {
    int b = -1;
    for (int k = 0; k < 16; ++k) if ((v >> k) & 1u) b = k;
    return b;
}

struct PlanT {
    int ngroups;
    int ng[NGMAX];
    unsigned char gl[NGMAX][GMAX];     // layer
    unsigned char gw[NGMAX][GMAX];     // wire
    unsigned short mloc[NGMAX][GMAX];  // 13-bit local mask
    unsigned short rloc[NGMAX][GMAX];  // 13-bit local row-parity vector
    unsigned short grow[NGMAX][GMAX];  // 16-bit global row (base parity)
    unsigned short V[NGMAX][BDIM];     // basis; V[0..5] == {1,2,4,8,16,32}
    unsigned short U[NGMAX][CDIM];     // complement unit vectors
    unsigned short frow[16];           // rows of final M^{-1}
    unsigned short floc[16];           // frow parities over last basis
    bool ok;
};

constexpr PlanT make_plan() {
    PlanT P{};
    P.ok = true;

    unsigned col[16] = {}, rowv[16] = {};
    for (int b = 0; b < 16; ++b) { col[b] = 1u << b; rowv[b] = 1u << b; }
    unsigned gmask[64] = {}, growg[64] = {};
    unsigned char glay[64] = {}, gwire[64] = {};
    int gi = 0;
    for (int l = 0; l < NL; ++l) {
        for (int w = 0; w < NQ; ++w) {
            const int b = 15 - w;
            gmask[gi] = col[b]; growg[gi] = rowv[b];
            glay[gi] = (unsigned char)l; gwire[gi] = (unsigned char)w; ++gi;
        }
        const int r = (l % (NQ - 1)) + 1;
        for (int w = 0; w < NQ; ++w) {
            const int cb = 15 - w;
            const int tb = 15 - ((w + r) % NQ);
            col[cb] ^= col[tb];      // M' = M * C
            rowv[tb] ^= rowv[cb];    // M'^{-1} = C * M^{-1}
        }
    }
    for (int b = 0; b < 16; ++b) P.frow[b] = (unsigned short)rowv[b];

    for (int a = 0; a < 16; ++a)
        for (int b2 = 0; b2 < 16; ++b2)
            if (parity16(rowv[a] & col[b2]) != (a == b2 ? 1 : 0)) P.ok = false;
    for (int i = 0; i < 64; ++i)
        if (parity16(gmask[i] & growg[i]) != 1) P.ok = false;

    bool applied[64] = {};
    int napplied = 0, grp = 0;
    while (napplied < 64) {
        if (grp >= NGMAX) { P.ok = false; break; }
        unsigned B[BDIM] = {}; int piv[BDIM] = {}; int nb = 0;
        for (int i = 0; i < 6; ++i) { B[i] = 1u << i; piv[i] = i; ++nb; }
        unsigned tmask[GMAX] = {}, trow[GMAX] = {};
        int cnt = 0;
        bool progress = true;
        while (progress) {
            progress = false;
            int lay = -1;
            for (int i = 0; i < 64; ++i)
                if (!applied[i]) { lay = glay[i]; break; }
            if (lay < 0) break;
            for (int w = 15; w >= 0; --w) {
                const int idx = lay * 16 + w;
                if (applied[idx]) continue;
                unsigned v = gmask[idx];
                for (int i = 0; i < nb; ++i) if ((v >> piv[i]) & 1u) v ^= B[i];
                if (v != 0u && nb == BDIM) continue;
                if (cnt >= GMAX) { P.ok = false; continue; }
                if (v != 0u) {
                    int pb = 0; while (((v >> pb) & 1u) == 0u) ++pb;
                    for (int i = 0; i < nb; ++i) if ((B[i] >> pb) & 1u) B[i] ^= v;
                    B[nb] = v; piv[nb] = pb; ++nb;
                }
                P.gl[grp][cnt] = glay[idx];
                P.gw[grp][cnt] = gwire[idx];
                tmask[cnt] = gmask[idx]; trow[cnt] = growg[idx];
                ++cnt;
                applied[idx] = true; ++napplied; progress = true;
            }
        }
        for (int bbit = 0; bbit < 16 && nb < BDIM; ++bbit) {
            unsigned v = 1u << bbit;
            for (int i = 0; i < nb; ++i) if ((v >> piv[i]) & 1u) v ^= B[i];
            if (v != 0u) {
                int pb = 0; while (((v >> pb) & 1u) == 0u) ++pb;
                for (int i = 0; i < nb; ++i) if ((B[i] >> pb) & 1u) B[i] ^= v;
                B[nb] = v; piv[nb] = pb; ++nb;
            }
        }
        if (nb != BDIM) P.ok = false;
        // value sort: seeds (1..32) stay in slots 0-5 (non-seeds >= 64)
        for (int i = 1; i < BDIM; ++i) {
            unsigned bv = B[i]; int pv = piv[i]; int j = i - 1;
            while (j >= 0 && B[j] > bv) { B[j+1] = B[j]; piv[j+1] = piv[j]; --j; }
            B[j+1] = bv; piv[j+1] = pv;
        }
        for (int i = 0; i < 6; ++i) if (B[i] != (1u << i)) P.ok = false;
        for (int i = 0; i < BDIM; ++i) P.V[grp][i] = (unsigned short)B[i];
        int cu = 0;
        for (int bbit = 0; bbit < 16; ++bbit) {
            bool isp = false;
            for (int i = 0; i < BDIM; ++i) if (piv[i] == bbit) isp = true;
            if (!isp) { if (cu < CDIM) P.U[grp][cu] = (unsigned short)(1u << bbit); ++cu; }
        }
        if (cu != CDIM) P.ok = false;
        for (int g = 0; g < cnt; ++g) {
            unsigned m = tmask[g], ml = 0;
            for (int i = 0; i < BDIM; ++i)
                if ((m >> piv[i]) & 1u) { ml |= 1u << i; m ^= B[i]; }
            if (m != 0u) P.ok = false;
            if (ml == 0u) P.ok = false;
            P.mloc[grp][g] = (unsigned short)ml;
            unsigned rl = 0;
            for (int i = 0; i < BDIM; ++i)
                rl |= (unsigned)parity16(trow[g] & B[i]) << i;
            P.rloc[grp][g] = (unsigned short)rl;
            P.grow[grp][g] = (unsigned short)trow[g];
        }
        P.ng[grp] = cnt;
        ++grp;
    }
    P.ngroups = grp;
    for (int q = 0; q < 16; ++q) {
        unsigned rl = 0;
        for (int s = 0; s < BDIM; ++s)
            rl |= (unsigned)parity16(P.frow[q] & P.V[P.ngroups - 1][s]) << s;
        P.floc[q] = (unsigned short)rl;
    }
    return P;
}

constexpr PlanT PLAN = make_plan();
static_assert(PLAN.ok, "constexpr plan construction failed");
static_assert(PLAN.ngroups >= 2 && PLAN.ngroups <= NGMAX, "unexpected group count");

// ---------------------------------------------------------------------------
// device code
// ---------------------------------------------------------------------------

__device__ __forceinline__ float xsgn(float v, unsigned sb) {
    return __uint_as_float(__float_as_uint(v) ^ sb);
}

template<int G>
__device__ __forceinline__ unsigned vmid(int tid) {   // tid bits 6..9
    unsigned rx = 0;
    if (tid & 64)  rx ^= PLAN.V[G][6];
    if (tid & 128) rx ^= PLAN.V[G][7];
    if (tid & 256) rx ^= PLAN.V[G][8];
    if (tid & 512) rx ^= PLAN.V[G][9];
    return rx;
}
template<int G>
__device__ __forceinline__ unsigned vhi(int j) {      // L bits 10..12
    unsigned rx = 0;
    if (j & 1) rx ^= PLAN.V[G][10];
    if (j & 2) rx ^= PLAN.V[G][11];
    if (j & 4) rx ^= PLAN.V[G][12];
    return rx;
}

// Gate coefficients: U00=(u0r,u0i), U01=(u1r,u1i); U11=conj(U00),
// U10=-conj(U01). Slot with branch parity p uses sign s=(p?-1:+1):
//   new = (u0r, s*u0i)*own + (s*u1r, u1i)*partner   (complex mul)
template<int G, int g>
__device__ __forceinline__ void apply_gates(float2* tile,
                                            const float* __restrict__ gu,
                                            unsigned base, int tid)
{
    if constexpr (g < PLAN.ng[G]) {
        constexpr unsigned ml  = PLAN.mloc[G][g];
        constexpr unsigned rl  = PLAN.rloc[G][g];
        constexpr unsigned grw = PLAN.grow[G][g];
        constexpr int gidx = PLAN.gl[G][g] * 16 + PLAN.gw[G][g];

        const float* up = gu + gidx * 8;  // uniform loads
        const float u0r = up[0], u0i = up[1], u1r = up[2], u1i = up[3];
        const int pgb = __popc(grw & base) & 1;

        if constexpr (ml < 64u) {
            // lane-only mask: own slot + shfl partner; no cross-wave traffic
            const int prt = (pgb ^ __popc(rl & (unsigned)tid)) & 1;
            #pragma unroll
            for (int j = 0; j < 8; ++j) {
                const int L = (j << 10) | tid;
                const float2 a = tile[L];
                const float bx = __shfl_xor(a.x, (int)ml, 64);
                const float by = __shfl_xor(a.y, (int)ml, 64);
                const int p = prt ^ (__popc(rl & ((unsigned)j << 10)) & 1); // folds
                const unsigned sb = (unsigned)p << 31;
                const float say = xsgn(a.y, sb), sax = xsgn(a.x, sb);
                const float sbx = xsgn(bx, sb),  sby = xsgn(by, sb);
                float2 o;
                o.x = u0r*a.x - u0i*say + u1r*sbx - u1i*by;
                o.y = u0r*a.y + u0i*sax + u1r*sby + u1i*bx;
                tile[L] = o;
            }
        } else {
            // pair path: expand 12-bit c by inserting 0 at highest mask bit
            // (hb >= 6 since ml >= 64) -> low 6 bits stay = lane: conflict-free.
            // Expansion is GF(2)-linear in c -> parity splits into a per-gate
            // thread part (etid) and a compile-time per-j part.
            constexpr int hb = topbit(ml);
            const unsigned etid = (((unsigned)tid >> hb) << (hb + 1)) |
                                  ((unsigned)tid & ((1u << hb) - 1u));
            const int ptid = (pgb ^ __popc(rl & etid)) & 1;
            #pragma unroll
            for (int j = 0; j < 4; ++j) {
                const unsigned cj = (unsigned)j << 10;
                const unsigned ej = ((cj >> hb) << (hb + 1)) |
                                    (cj & ((1u << hb) - 1u));       // folds
                const unsigned i = etid | ej;   // disjoint bit sets
                const unsigned k = i ^ ml;
                const float2 a = tile[i];
                const float2 b = tile[k];
                const int p = ptid ^ (__popc(rl & ej) & 1);          // folds
                const unsigned sb = (unsigned)p << 31;
                const float say = xsgn(a.y, sb), sax = xsgn(a.x, sb);
                const float sbx = xsgn(b.x, sb), sby = xsgn(b.y, sb);
                float2 oi, ok;
                oi.x = u0r*a.x - u0i*say + u1r*sbx - u1i*b.y;
                oi.y = u0r*a.y + u0i*sax + u1r*sby + u1i*b.x;
                // partner parity = p^1 (row.mask==1) -> sign flipped
                ok.x = u0r*b.x + u0i*sby - u1r*sax - u1i*a.y;
                ok.y = u0r*b.y - u0i*sbx - u1r*say + u1i*a.x;
                tile[i] = oi; tile[k] = ok;
            }
        }
        // barrier unless this gate was lane-only AND the next consumer only
        // reads own slots (next lane gate, or the store/measure epilogue)
        constexpr bool cur_lane  = (ml < 64u);
        constexpr bool next_lane = (g + 1 < PLAN.ng[G]) &&
                                   (PLAN.mloc[G][g + 1] < 64u);
        constexpr bool last_gate = (g + 1 >= PLAN.ng[G]);
        if constexpr (!(cur_lane && (next_lane || last_gate))) __syncthreads();
        apply_gates<G, g + 1>(tile, gu, base, tid);
    }
}

// one 1024-thread WG (16 waves) = one (batch, coset) tile of 2^13
// amplitudes in LDS, 8 slots/thread. 2 WGs/CU (LDS 2x64 KiB) = 32
// waves/CU = HW max. launch_bounds(1024,8) clamps VGPR<=64 (natural ~52).
template<int G, bool FIRST, bool LAST>
__global__ __launch_bounds__(1024, 8)
void pass_kernel(const float* __restrict__ x,
                 const float* __restrict__ gu,
                 float2* __restrict__ state,
                 const float* __restrict__ invn,
                 float* __restrict__ zpart)
{
    __shared__ float2 tile[1 << 13];   // 64 KiB
    const int tid = (int)threadIdx.x;
    const int batch = (int)blockIdx.x >> 3;
    const unsigned coset = (unsigned)blockIdx.x & 7u;

    unsigned base = 0;
    if (coset & 1u) base ^= PLAN.U[G][0];
    if (coset & 2u) base ^= PLAN.U[G][1];
    if (coset & 4u) base ^= PLAN.U[G][2];
    // lane dims are literal bits 0-5 -> 512B-contiguous per wave
    const unsigned gbt = base ^ (unsigned)(tid & 63) ^ vmid<G>(tid);
    const int boff = batch << 16;

    if constexpr (FIRST) {
        const float inv = invn[batch];
        #pragma unroll
        for (int j = 0; j < 8; ++j)
            tile[(j << 10) | tid] =
                make_float2(x[boff + (int)(gbt ^ vhi<G>(j))] * inv, 0.f);
    } else {
        #pragma unroll
        for (int j = 0; j < 8; ++j)
            tile[(j << 10) | tid] = state[boff + (int)(gbt ^ vhi<G>(j))];
    }
    // load writes own slots; skip barrier if first gate is lane-only
    if constexpr (!(PLAN.ng[G] > 0 && PLAN.mloc[G][0] < 64u)) __syncthreads();

    apply_gates<G, 0>(tile, gu, base, tid);

    if constexpr (LAST) {
        // <Z_q> partials; sign(slot L) = parity(frow[q]&base) ^ parity(floc[q]&L)
        unsigned sbits = 0;
        #pragma unroll
        for (int q = 0; q < 16; ++q) {
            const int s0 = (__popc((unsigned)PLAN.frow[q] & base)
                          + __popc((unsigned)PLAN.floc[q] & (unsigned)tid)) & 1;
            sbits |= (unsigned)s0 << q;
        }
        const int wave = tid >> 6, lane = tid & 63;
        const int W = (int)blockIdx.x * 16 + wave;
        #pragma unroll
        for (int h = 0; h < 2; ++h) {          // two halves of 8 q's (VGPR)
            float acc[8] = {0,0,0,0,0,0,0,0};
            #pragma unroll
            for (int j = 0; j < 8; ++j) {
                const float2 a = tile[(j << 10) | tid];
                const float pr = a.x*a.x + a.y*a.y;
                #pragma unroll
                for (int q8 = 0; q8 < 8; ++q8) {
                    const int q = h * 8 + q8;
                    const int s = (int)((sbits >> q) & 1u) ^
                        (__popc((unsigned)PLAN.floc[q] & ((unsigned)j << 10)) & 1);
                    acc[q8] += s ? -pr : pr;
                }
            }
            #pragma unroll
            for (int q8 = 0; q8 < 8; ++q8) {
                float v = acc[q8];
                #pragma unroll
                for (int o = 32; o; o >>= 1) v += __shfl_xor(v, o, 64);
                if (lane == 0) zpart[W * 16 + h * 8 + q8] = v;
            }
        }
    } else {
        #pragma unroll
        for (int j = 0; j < 8; ++j)
            state[boff + (int)(gbt ^ vhi<G>(j))] = tile[(j << 10) | tid];
    }
}

__global__ __launch_bounds__(256)
void norm_kernel(const float* __restrict__ x, float* __restrict__ invn)
{
    const int b = (int)blockIdx.x;
    const float4* xv = reinterpret_cast<const float4*>(x + ((size_t)b << 16));
    float s = 0.f;
    for (int i = (int)threadIdx.x; i < 16384; i += 256) {
        const float4 v = xv[i];
        s += v.x*v.x + v.y*v.y + v.z*v.z + v.w*v.w;
    }
    #pragma unroll
    for (int o = 32; o; o >>= 1) s += __shfl_xor(s, o, 64);
    __shared__ float partial[4];
    if ((threadIdx.x & 63u) == 0u) partial[threadIdx.x >> 6] = s;
    __syncthreads();
    if (threadIdx.x == 0) {
        const float t = partial[0] + partial[1] + partial[2] + partial[3];
        invn[b] = 1.0f / sqrtf(t);
    }
}

// precompute the 64 Rot matrices (PennyLane Rot = RZ(om) RY(th) RZ(phi))
__global__ void gateu_kernel(const float* __restrict__ wts, float* __restrict__ gu)
{
    const int i = (int)threadIdx.x;  // gate index l*16+w
    if (i < 64) {
        const float phi = wts[i*3+0], th = wts[i*3+1], om = wts[i*3+2];
        float sh, ch; sincosf(0.5f * th, &sh, &ch);
        float sap, cap; sincosf(0.5f * (phi + om), &sap, &cap);
        float sam, cam; sincosf(0.5f * (phi - om), &sam, &cam);
        gu[i*8+0] =  cap*ch;  gu[i*8+1] = -sap*ch;   // U00
        gu[i*8+2] = -cam*sh;  gu[i*8+3] = -sam*sh;   // U01
        gu[i*8+4] =  cam*sh;  gu[i*8+5] = -sam*sh;   // U10 (unused on device)
        gu[i*8+6] =  cap*ch;  gu[i*8+7] =  sap*ch;   // U11 (unused on device)
    }
}

__global__ __launch_bounds__(1024)
void out_kernel(const float* __restrict__ zpart, const float* __restrict__ cw,
                const float* __restrict__ cb, float* __restrict__ out)
{
    const int b = (int)blockIdx.x;
    const int q = (int)(threadIdx.x >> 6);   // one wave per qubit
    const int c = (int)(threadIdx.x & 63u);  // 128 partials per (b,q)
    float v = zpart[(size_t)(((b << 7) | c) * 16 + q)]
            + zpart[(size_t)(((b << 7) | c | 64) * 16 + q)];
    #pragma unroll
    for (int o = 32; o; o >>= 1) v += __shfl_xor(v, o, 64);
    __shared__ float z[16];
    if (c == 0) z[q] = v;
    __syncthreads();
    if (threadIdx.x < 2) {
        const int o = (int)threadIdx.x;
        float acc = cb[o];
        #pragma unroll
        for (int w = 0; w < 16; ++w) acc += cw[o * 16 + w] * z[15 - w];
        out[b * 2 + o] = acc;
    }
}

__global__ void sentinel_kernel(float* out)
{
    if (threadIdx.x < 256) out[threadIdx.x] = -12345.0f;  // ws too small marker
}

template<int I>
static void launch_one(const float* x, const float* gu, float2* state,
                       const float* invn, float* zpart, hipStream_t s)
{
    pass_kernel<I, I == 0, I == PLAN.ngroups - 1>
        <<<1024, 1024, 0, s>>>(x, gu, state, invn, zpart);
}

template<std::size_t... I>
static void launch_all(std::index_sequence<I...>, const float* x, const float* gu,
                       float2* state, const float* invn, float* zpart, hipStream_t s)
{
    (launch_one<(int)I>(x, gu, state, invn, zpart, s), ...);
}

} // namespace qsim

extern "C" void kernel_launch(void* const* d_in, const int* in_sizes, int n_in,
                              void* d_out, int out_size, void* d_ws, size_t ws_size,
                              hipStream_t stream)
{
    (void)in_sizes; (void)n_in; (void)out_size;
    const float* x   = (const float*)d_in[0];   // (128,256,256) f32
    const float* wts = (const float*)d_in[1];   // (4,16,3) f32
    const float* cw  = (const float*)d_in[2];   // (2,16) f32
    const float* cb  = (const float*)d_in[3];   // (2,) f32
    float* out = (float*)d_out;                 // (128,2) f32

    constexpr size_t STATE_BYTES = (size_t)128 * 65536 * sizeof(float2); // 64 MiB
    constexpr size_t INVN_OFF  = STATE_BYTES;                  // 128 floats
    constexpr size_t GATEU_OFF = STATE_BYTES + 1024;           // 64*8 floats
    constexpr size_t ZPART_OFF = STATE_BYTES + 1024 + 4096;
    constexpr size_t ZPART_BYTES = (size_t)1024 * 16 * 16 * sizeof(float); // 1 MiB
    constexpr size_t NEED = ZPART_OFF + ZPART_BYTES;

    if (ws_size < NEED) {
        qsim::sentinel_kernel<<<1, 256, 0, stream>>>(out);
        return;
    }

    float2* state = (float2*)d_ws;
    float* invn   = (float*)((char*)d_ws + INVN_OFF);
    float* gu     = (float*)((char*)d_ws + GATEU_OFF);
    float* zpart  = (float*)((char*)d_ws + ZPART_OFF);

    qsim::norm_kernel<<<128, 256, 0, stream>>>(x, invn);
    qsim::gateu_kernel<<<1, 64, 0, stream>>>(wts, gu);
    qsim::launch_all(std::make_index_sequence<(std::size_t)qsim::PLAN.ngroups>{},
                     x, gu, state, invn, zpart, stream);
    qsim::out_kernel<<<128, 1024, 0, stream>>>(zpart, cw, cb, out);
}